// Round 3
// baseline (1649.825 us; speedup 1.0000x reference)
//
#include <hip/hip_runtime.h>
#include <math.h>

#define SEQ_L 2048
#define DM 1024
#define NH 16
#define HD 64
#define NB 2
#define KD 1024   // GEMM K
#define ND 1024   // GEMM N

typedef __bf16 bf16;
typedef __bf16 bf16x8 __attribute__((ext_vector_type(8)));
typedef float f32x4 __attribute__((ext_vector_type(4)));

// ---------------- conversions ----------------
__global__ void cvt_x_kernel(const float* __restrict__ in, bf16* __restrict__ out, int n) {
  int i = blockIdx.x * 256 + threadIdx.x;
  if (i < n) out[i] = (bf16)in[i];
}

__global__ void cvt_w_kernel(const float* __restrict__ w0, const float* __restrict__ w1,
                             const float* __restrict__ w2, const float* __restrict__ w3,
                             bf16* __restrict__ o0, bf16* __restrict__ o1,
                             bf16* __restrict__ o2, bf16* __restrict__ o3) {
  int i = blockIdx.x * 256 + threadIdx.x;
  const float* w; bf16* o;
  switch (blockIdx.y) {
    case 0: w = w0; o = o0; break;
    case 1: w = w1; o = o1; break;
    case 2: w = w2; o = o2; break;
    default: w = w3; o = o3; break;
  }
  o[i] = (bf16)w[i];
}

// ---------------- GEMM: C[m][n] = sum_k A[m][k] * W[n][k]  (B^T layout, m97 pattern) ----------------
__device__ inline void gld16(const bf16* g, bf16* l) {
  __builtin_amdgcn_global_load_lds((const __attribute__((address_space(1))) void*)g,
                                   (__attribute__((address_space(3))) void*)l, 16, 0, 0);
}

template <typename OutT>
__device__ inline void gemm_bt_body(const bf16* __restrict__ A, const bf16* __restrict__ W,
                                    OutT* __restrict__ C) {
  __shared__ __align__(16) bf16 As[128 * 32];
  __shared__ __align__(16) bf16 Bs[128 * 32];
  const int t = threadIdx.x;
  const int lane = t & 63;
  const int wave = t >> 6;
  const int wm = (wave >> 1) * 64;
  const int wn = (wave & 1) * 64;
  const int m0 = blockIdx.x * 128;
  const int n0 = blockIdx.y * 128;
  const int r = t >> 2;            // staging row 0..63
  const int ck = (t & 3) * 8;      // staging k-chunk (8 bf16 = 16B)
  const int l15 = lane & 15;
  const int koff = (lane >> 4) * 8;

  f32x4 acc[4][4] = {};

  for (int k0 = 0; k0 < KD; k0 += 32) {
    gld16(A + (size_t)(m0 + r) * KD + k0 + ck, As + t * 8);
    gld16(A + (size_t)(m0 + 64 + r) * KD + k0 + ck, As + 2048 + t * 8);
    gld16(W + (size_t)(n0 + r) * KD + k0 + ck, Bs + t * 8);
    gld16(W + (size_t)(n0 + 64 + r) * KD + k0 + ck, Bs + 2048 + t * 8);
    __syncthreads();
    bf16x8 af[4], bfr[4];
#pragma unroll
    for (int mt = 0; mt < 4; ++mt)
      af[mt] = *(const bf16x8*)(As + (wm + mt * 16 + l15) * 32 + koff);
#pragma unroll
    for (int nt = 0; nt < 4; ++nt)
      bfr[nt] = *(const bf16x8*)(Bs + (wn + nt * 16 + l15) * 32 + koff);
#pragma unroll
    for (int mt = 0; mt < 4; ++mt)
#pragma unroll
      for (int nt = 0; nt < 4; ++nt)
        acc[mt][nt] = __builtin_amdgcn_mfma_f32_16x16x32_bf16(af[mt], bfr[nt], acc[mt][nt], 0, 0, 0);
    __syncthreads();
  }
  // C/D layout: col = lane&15, row = (lane>>4)*4 + reg   [verified m89]
  const int colb = n0 + wn + l15;
  const int rowb = m0 + wm + (lane >> 4) * 4;
#pragma unroll
  for (int mt = 0; mt < 4; ++mt)
#pragma unroll
    for (int nt = 0; nt < 4; ++nt)
#pragma unroll
      for (int rr = 0; rr < 4; ++rr)
        C[(size_t)(rowb + mt * 16 + rr) * ND + colb + nt * 16] = (OutT)acc[mt][nt][rr];
}

__global__ __launch_bounds__(256, 2) void qkv_gemm_kernel(
    const bf16* __restrict__ xb, const bf16* __restrict__ wqb, const bf16* __restrict__ wkb,
    const bf16* __restrict__ wvb, bf16* __restrict__ qb, bf16* __restrict__ kb, bf16* __restrict__ vb) {
  const bf16* W = blockIdx.z == 0 ? wqb : blockIdx.z == 1 ? wkb : wvb;
  bf16* O = blockIdx.z == 0 ? qb : blockIdx.z == 1 ? kb : vb;
  gemm_bt_body<bf16>(xb, W, O);
}

__global__ __launch_bounds__(256, 2) void out_gemm_kernel(
    const bf16* __restrict__ ab, const bf16* __restrict__ wob, float* __restrict__ out) {
  gemm_bt_body<float>(ab, wob, out);
}

// ---------------- RoPE (in place on q,k; layout [B,L,H,HD]) ----------------
__global__ void rope_kernel(bf16* __restrict__ q, bf16* __restrict__ k, const float* __restrict__ freqs) {
  int idx = blockIdx.x * 256 + threadIdx.x;     // over B*L*NH*32 = 2097152 pairs
  int jj = idx & 31;
  int bl = idx >> 9;                            // b*SEQ_L + l
  int l = bl & (SEQ_L - 1);
  float ang = freqs[l * 32 + jj];
  float s, c;
  sincosf(ang, &s, &c);
  size_t base = (size_t)idx * 2;
  float qre = (float)q[base], qim = (float)q[base + 1];
  q[base]     = (bf16)(qre * c - qim * s);
  q[base + 1] = (bf16)(qre * s + qim * c);
  float kre = (float)k[base], kim = (float)k[base + 1];
  k[base]     = (bf16)(kre * c - kim * s);
  k[base + 1] = (bf16)(kre * s + kim * c);
}

// ---------------- jax threefry2x32, key = (0, 42) ----------------
__device__ inline uint32_t rotl32(uint32_t v, int n) { return (v << n) | (v >> (32 - n)); }

__device__ inline void threefry(uint32_t x0, uint32_t x1, uint32_t* o0, uint32_t* o1) {
  const uint32_t ks0 = 0u, ks1 = 42u, ks2 = 0u ^ 42u ^ 0x1BD11BDAu;
  x0 += ks0; x1 += ks1;
#define TF_R(rr) { x0 += x1; x1 = rotl32(x1, rr); x1 ^= x0; }
  TF_R(13) TF_R(15) TF_R(26) TF_R(6)
  x0 += ks1; x1 += ks2 + 1u;
  TF_R(17) TF_R(29) TF_R(16) TF_R(24)
  x0 += ks2; x1 += ks0 + 2u;
  TF_R(13) TF_R(15) TF_R(26) TF_R(6)
  x0 += ks0; x1 += ks1 + 3u;
  TF_R(17) TF_R(29) TF_R(16) TF_R(24)
  x0 += ks1; x1 += ks2 + 4u;
  TF_R(13) TF_R(15) TF_R(26) TF_R(6)
  x0 += ks2; x1 += ks0 + 5u;
#undef TF_R
  *o0 = x0; *o1 = x1;
}

// jax_threefry_partitionable=True (modern default) random_bits for uint32:
// per-element 64-bit counter = flat index (iota_2x32_shape -> (hi=0, lo=f));
// bits = o0 ^ o1 of threefry(key, (0, f)).
__device__ inline int rand_col(int i, int s) {
  uint32_t f = (uint32_t)(2 * i + s);
  uint32_t o0, o1;
  threefry(0u, f, &o0, &o1);
  uint32_t bits = o0 ^ o1;
  float u = __uint_as_float((bits >> 9) | 0x3f800000u) - 1.0f;
  return (int)floorf(u * (float)(i + 1));
}

// ---------------- unified attention: one wave per (b,h,i), ALL rows ----------------
// mask(i,j) = (i==0) | (j==0) | (j<=i & (i-j<=7 | j==r0 | j==r1)); online softmax.
__global__ __launch_bounds__(64) void attn_kernel(const bf16* __restrict__ q, const bf16* __restrict__ k,
                                                  const bf16* __restrict__ v, bf16* __restrict__ o) {
  const int i = blockIdx.x;
  const int h = blockIdx.y;
  const int b = blockIdx.z;
  const int lane = threadIdx.x;
  const size_t hb = (size_t)b * SEQ_L * DM + (size_t)h * HD;

  const float qd = (float)q[hb + (size_t)i * DM + lane];
  const bool row0 = (i == 0);
  const int r0 = rand_col(i, 0);
  const int r1 = rand_col(i, 1);
  const int jmax = row0 ? (SEQ_L - 1) : i;
  const int cmax = jmax >> 6;

  float m = -1e30f, z = 0.f, oacc = 0.f;
  for (int c = 0; c <= cmax; ++c) {
    if (!row0) {
      // chunk [c*64, c*64+63] can contain an allowed column?
      bool rel = (c == 0) | (c == (r0 >> 6)) | (c == (r1 >> 6)) |
                 ((c * 64 + 63 >= i - 7) & (c * 64 <= i));
      if (!rel) continue;       // wave-uniform branch
    }
    int jend = c * 64 + 63; if (jend > jmax) jend = jmax;
    for (int j = c * 64; j <= jend; ++j) {
      bool ok = row0 || (j == 0) || (i - j <= 7) || (j == r0) || (j == r1);
      if (!ok) continue;        // wave-uniform branch
      float s = qd * (float)k[hb + (size_t)j * DM + lane];
#pragma unroll
      for (int off = 32; off > 0; off >>= 1) s += __shfl_xor(s, off);
      s *= 0.125f;
      float mn = fmaxf(m, s);
      float corr = __expf(m - mn);   // first accepted col: exp(-inf) = 0
      float e = __expf(s - mn);
      z = z * corr + e;
      oacc = oacc * corr + e * (float)v[hb + (size_t)j * DM + lane];
      m = mn;
    }
  }
  o[hb + (size_t)i * DM + lane] = (bf16)(oacc / z);
}

// ---------------- launch ----------------
extern "C" void kernel_launch(void* const* d_in, const int* in_sizes, int n_in,
                              void* d_out, int out_size, void* d_ws, size_t ws_size,
                              hipStream_t stream) {
  const float* x     = (const float*)d_in[0];
  const float* freqs = (const float*)d_in[1];
  const float* wq    = (const float*)d_in[2];
  const float* wk    = (const float*)d_in[3];
  const float* wv    = (const float*)d_in[4];
  const float* wo    = (const float*)d_in[5];
  float* out = (float*)d_out;

  char* ws = (char*)d_ws;
  bf16* xb  = (bf16*)(ws + 0);          // 8 MiB  [4096,1024]
  bf16* wqb = (bf16*)(ws + 8388608);    // 2 MiB each
  bf16* wkb = (bf16*)(ws + 10485760);
  bf16* wvb = (bf16*)(ws + 12582912);
  bf16* wob = (bf16*)(ws + 14680064);
  bf16* qb  = (bf16*)(ws + 16777216);   // 8 MiB [B,L,H,HD]
  bf16* kb  = (bf16*)(ws + 25165824);
  bf16* vb  = (bf16*)(ws + 33554432);
  bf16* ab  = (bf16*)(ws + 41943040);   // attn out, 8 MiB; total 48 MiB
  (void)ws_size;

  cvt_x_kernel<<<16384, 256, 0, stream>>>(x, xb, NB * SEQ_L * DM);
  cvt_w_kernel<<<dim3(4096, 4), 256, 0, stream>>>(wq, wk, wv, wo, wqb, wkb, wvb, wob);
  qkv_gemm_kernel<<<dim3(32, 8, 3), 256, 0, stream>>>(xb, wqb, wkb, wvb, qb, kb, vb);
  rope_kernel<<<8192, 256, 0, stream>>>(qb, kb, freqs);
  attn_kernel<<<dim3(SEQ_L, NH, NB), 64, 0, stream>>>(qb, kb, vb, ab);
  out_gemm_kernel<<<dim3(32, 8), 256, 0, stream>>>(ab, wob, out);
}

// Round 4
// 337.067 us; speedup vs baseline: 4.8946x; 4.8946x over previous
//
#include <hip/hip_runtime.h>
#include <math.h>

#define SEQ_L 2048
#define DM 1024
#define NH 16
#define HD 64
#define NB 2
#define KD 1024   // GEMM K
#define ND 1024   // GEMM N

typedef __bf16 bf16;
typedef __bf16 bf16x8 __attribute__((ext_vector_type(8)));
typedef float f32x4 __attribute__((ext_vector_type(4)));

// ---------------- conversions ----------------
__global__ void cvt_x_kernel(const float* __restrict__ in, bf16* __restrict__ out, int n) {
  int i = blockIdx.x * 256 + threadIdx.x;
  if (i < n) out[i] = (bf16)in[i];
}

__global__ void cvt_w_kernel(const float* __restrict__ w0, const float* __restrict__ w1,
                             const float* __restrict__ w2, const float* __restrict__ w3,
                             bf16* __restrict__ o0, bf16* __restrict__ o1,
                             bf16* __restrict__ o2, bf16* __restrict__ o3) {
  int i = blockIdx.x * 256 + threadIdx.x;
  const float* w; bf16* o;
  switch (blockIdx.y) {
    case 0: w = w0; o = o0; break;
    case 1: w = w1; o = o1; break;
    case 2: w = w2; o = o2; break;
    default: w = w3; o = o3; break;
  }
  o[i] = (bf16)w[i];
}

// ---------------- GEMM: C[m][n] = sum_k A[m][k] * W[n][k]  (B^T layout, m97 pattern) ----------------
__device__ inline void gld16(const bf16* g, bf16* l) {
  __builtin_amdgcn_global_load_lds((const __attribute__((address_space(1))) void*)g,
                                   (__attribute__((address_space(3))) void*)l, 16, 0, 0);
}

template <typename OutT>
__device__ inline void gemm_bt_body(const bf16* __restrict__ A, const bf16* __restrict__ W,
                                    OutT* __restrict__ C) {
  __shared__ __align__(16) bf16 As[128 * 32];
  __shared__ __align__(16) bf16 Bs[128 * 32];
  const int t = threadIdx.x;
  const int lane = t & 63;
  const int wave = t >> 6;
  const int wm = (wave >> 1) * 64;
  const int wn = (wave & 1) * 64;
  const int m0 = blockIdx.x * 128;
  const int n0 = blockIdx.y * 128;
  const int r = t >> 2;            // staging row 0..63
  const int ck = (t & 3) * 8;      // staging k-chunk (8 bf16 = 16B)
  const int l15 = lane & 15;
  const int koff = (lane >> 4) * 8;

  f32x4 acc[4][4] = {};

  for (int k0 = 0; k0 < KD; k0 += 32) {
    gld16(A + (size_t)(m0 + r) * KD + k0 + ck, As + t * 8);
    gld16(A + (size_t)(m0 + 64 + r) * KD + k0 + ck, As + 2048 + t * 8);
    gld16(W + (size_t)(n0 + r) * KD + k0 + ck, Bs + t * 8);
    gld16(W + (size_t)(n0 + 64 + r) * KD + k0 + ck, Bs + 2048 + t * 8);
    __syncthreads();
    bf16x8 af[4], bfr[4];
#pragma unroll
    for (int mt = 0; mt < 4; ++mt)
      af[mt] = *(const bf16x8*)(As + (wm + mt * 16 + l15) * 32 + koff);
#pragma unroll
    for (int nt = 0; nt < 4; ++nt)
      bfr[nt] = *(const bf16x8*)(Bs + (wn + nt * 16 + l15) * 32 + koff);
#pragma unroll
    for (int mt = 0; mt < 4; ++mt)
#pragma unroll
      for (int nt = 0; nt < 4; ++nt)
        acc[mt][nt] = __builtin_amdgcn_mfma_f32_16x16x32_bf16(af[mt], bfr[nt], acc[mt][nt], 0, 0, 0);
    __syncthreads();
  }
  // C/D layout: col = lane&15, row = (lane>>4)*4 + reg   [verified m89]
  const int colb = n0 + wn + l15;
  const int rowb = m0 + wm + (lane >> 4) * 4;
#pragma unroll
  for (int mt = 0; mt < 4; ++mt)
#pragma unroll
    for (int nt = 0; nt < 4; ++nt)
#pragma unroll
      for (int rr = 0; rr < 4; ++rr)
        C[(size_t)(rowb + mt * 16 + rr) * ND + colb + nt * 16] = (OutT)acc[mt][nt][rr];
}

__global__ __launch_bounds__(256, 2) void qkv_gemm_kernel(
    const bf16* __restrict__ xb, const bf16* __restrict__ wqb, const bf16* __restrict__ wkb,
    const bf16* __restrict__ wvb, bf16* __restrict__ qb, bf16* __restrict__ kb, bf16* __restrict__ vb) {
  const bf16* W = blockIdx.z == 0 ? wqb : blockIdx.z == 1 ? wkb : wvb;
  bf16* O = blockIdx.z == 0 ? qb : blockIdx.z == 1 ? kb : vb;
  gemm_bt_body<bf16>(xb, W, O);
}

__global__ __launch_bounds__(256, 2) void out_gemm_kernel(
    const bf16* __restrict__ ab, const bf16* __restrict__ wob, float* __restrict__ out) {
  gemm_bt_body<float>(ab, wob, out);
}

// ---------------- RoPE (in place on q,k; layout [B,L,H,HD]) ----------------
__global__ void rope_kernel(bf16* __restrict__ q, bf16* __restrict__ k, const float* __restrict__ freqs) {
  int idx = blockIdx.x * 256 + threadIdx.x;     // over B*L*NH*32 = 2097152 pairs
  int jj = idx & 31;
  int bl = idx >> 9;                            // b*SEQ_L + l
  int l = bl & (SEQ_L - 1);
  float ang = freqs[l * 32 + jj];
  float s, c;
  sincosf(ang, &s, &c);
  size_t base = (size_t)idx * 2;
  float qre = (float)q[base], qim = (float)q[base + 1];
  q[base]     = (bf16)(qre * c - qim * s);
  q[base + 1] = (bf16)(qre * s + qim * c);
  float kre = (float)k[base], kim = (float)k[base + 1];
  k[base]     = (bf16)(kre * c - kim * s);
  k[base + 1] = (bf16)(kre * s + kim * c);
}

// ---------------- jax threefry2x32, key = (0, 42); partitionable random_bits ----------------
__device__ inline uint32_t rotl32(uint32_t v, int n) { return (v << n) | (v >> (32 - n)); }

__device__ inline void threefry(uint32_t x0, uint32_t x1, uint32_t* o0, uint32_t* o1) {
  const uint32_t ks0 = 0u, ks1 = 42u, ks2 = 0u ^ 42u ^ 0x1BD11BDAu;
  x0 += ks0; x1 += ks1;
#define TF_R(rr) { x0 += x1; x1 = rotl32(x1, rr); x1 ^= x0; }
  TF_R(13) TF_R(15) TF_R(26) TF_R(6)
  x0 += ks1; x1 += ks2 + 1u;
  TF_R(17) TF_R(29) TF_R(16) TF_R(24)
  x0 += ks2; x1 += ks0 + 2u;
  TF_R(13) TF_R(15) TF_R(26) TF_R(6)
  x0 += ks0; x1 += ks1 + 3u;
  TF_R(17) TF_R(29) TF_R(16) TF_R(24)
  x0 += ks1; x1 += ks2 + 4u;
  TF_R(13) TF_R(15) TF_R(26) TF_R(6)
  x0 += ks2; x1 += ks0 + 5u;
#undef TF_R
  *o0 = x0; *o1 = x1;
}

// jax_threefry_partitionable=True: counter (hi=0, lo=flat_idx), bits = o0 ^ o1.
__device__ inline int rand_col(int i, int s) {
  uint32_t o0, o1;
  threefry(0u, (uint32_t)(2 * i + s), &o0, &o1);
  uint32_t bits = o0 ^ o1;
  float u = __uint_as_float((bits >> 9) | 0x3f800000u) - 1.0f;
  return (int)floorf(u * (float)(i + 1));
}

// ---------------- attention, single launch ----------------
// grid (513, NH, NB), 256 threads.
//  blockIdx.x < 512 : 4 waves, wave w handles row i = 1 + 4*bx + w (column-list form,
//                     all ~11 k-loads/v-loads independent -> pipelined).
//  blockIdx.x == 512: dense row 0, parallelized over columns (256 threads x 8 cols),
//                     block softmax, 4-way-split weighted V sum.
__global__ __launch_bounds__(256) void attn_kernel(const bf16* __restrict__ q, const bf16* __restrict__ k,
                                                   const bf16* __restrict__ v, bf16* __restrict__ o) {
  const int h = blockIdx.y;
  const int b = blockIdx.z;
  const size_t hb = (size_t)b * SEQ_L * DM + (size_t)h * HD;
  const int t = threadIdx.x;
  const int lane = t & 63;
  const int w = t >> 6;

  __shared__ float pbuf[SEQ_L];
  __shared__ float redm[4], redz[4];
  __shared__ float part[4][64];

  if (blockIdx.x < 512) {
    const int i = 1 + blockIdx.x * 4 + w;
    if (i >= SEQ_L) return;   // wave-uniform

    const float qd = (float)q[hb + (size_t)i * DM + lane];

    // columns: window [max(0,i-7)..i] ∪ {0} ∪ {r0,r1} deduped (≤11)
    int cols[11]; int nc = 0;
    int lo = i - 7; if (lo < 0) lo = 0;
    for (int j = lo; j <= i; ++j) cols[nc++] = j;
    if (lo > 0) cols[nc++] = 0;
#pragma unroll
    for (int s = 0; s < 2; ++s) {
      int rj = rand_col(i, s);
      bool dup = false;
      for (int c2 = 0; c2 < nc; ++c2) dup |= (cols[c2] == rj);
      if (!dup) cols[nc++] = rj;
    }
    for (int c2 = nc; c2 < 11; ++c2) cols[c2] = -1;

    float sv[11];
#pragma unroll
    for (int c2 = 0; c2 < 11; ++c2) {
      int cj = cols[c2] < 0 ? 0 : cols[c2];
      float s2 = qd * (float)k[hb + (size_t)cj * DM + lane];
      sv[c2] = s2;
    }
#pragma unroll
    for (int c2 = 0; c2 < 11; ++c2) {
#pragma unroll
      for (int off = 32; off > 0; off >>= 1) sv[c2] += __shfl_xor(sv[c2], off);
      sv[c2] = cols[c2] < 0 ? -1e30f : sv[c2] * 0.125f;
    }
    float m = -1e30f;
#pragma unroll
    for (int c2 = 0; c2 < 11; ++c2) m = fmaxf(m, sv[c2]);
    float z = 0.f;
#pragma unroll
    for (int c2 = 0; c2 < 11; ++c2) { sv[c2] = __expf(sv[c2] - m); z += sv[c2]; }
    float oacc = 0.f;
#pragma unroll
    for (int c2 = 0; c2 < 11; ++c2) {
      int cj = cols[c2] < 0 ? 0 : cols[c2];
      oacc += sv[c2] * (float)v[hb + (size_t)cj * DM + lane];
    }
    o[hb + (size_t)i * DM + lane] = (bf16)(oacc / z);
    return;
  }

  // ---- dense row 0 ----
  bf16x8 qv[8];
#pragma unroll
  for (int c = 0; c < 8; ++c) qv[c] = *(const bf16x8*)(q + hb + c * 8);

  float mloc = -1e30f;
  for (int j = t; j < SEQ_L; j += 256) {
    float acc = 0.f;
#pragma unroll
    for (int c = 0; c < 8; ++c) {
      bf16x8 kv = *(const bf16x8*)(k + hb + (size_t)j * DM + c * 8);
#pragma unroll
      for (int e = 0; e < 8; ++e) acc += (float)qv[c][e] * (float)kv[e];
    }
    float s = acc * 0.125f;
    pbuf[j] = s;
    mloc = fmaxf(mloc, s);
  }
#pragma unroll
  for (int off = 32; off > 0; off >>= 1) mloc = fmaxf(mloc, __shfl_xor(mloc, off));
  if (lane == 0) redm[w] = mloc;
  __syncthreads();
  const float m = fmaxf(fmaxf(redm[0], redm[1]), fmaxf(redm[2], redm[3]));

  float zloc = 0.f;
  for (int j = t; j < SEQ_L; j += 256) {
    float e = __expf(pbuf[j] - m);
    pbuf[j] = e;
    zloc += e;
  }
#pragma unroll
  for (int off = 32; off > 0; off >>= 1) zloc += __shfl_xor(zloc, off);
  if (lane == 0) redz[w] = zloc;
  __syncthreads();
  const float z = redz[0] + redz[1] + redz[2] + redz[3];

  // weighted V: wave w covers j ≡ w (mod 4); lane = d
  float oa = 0.f;
  for (int j = w; j < SEQ_L; j += 4)
    oa += pbuf[j] * (float)v[hb + (size_t)j * DM + lane];
  part[w][lane] = oa;
  __syncthreads();
  if (t < 64)
    o[hb + t] = (bf16)((part[0][t] + part[1][t] + part[2][t] + part[3][t]) / z);
}

// ---------------- launch ----------------
extern "C" void kernel_launch(void* const* d_in, const int* in_sizes, int n_in,
                              void* d_out, int out_size, void* d_ws, size_t ws_size,
                              hipStream_t stream) {
  const float* x     = (const float*)d_in[0];
  const float* freqs = (const float*)d_in[1];
  const float* wq    = (const float*)d_in[2];
  const float* wk    = (const float*)d_in[3];
  const float* wv    = (const float*)d_in[4];
  const float* wo    = (const float*)d_in[5];
  float* out = (float*)d_out;

  char* ws = (char*)d_ws;
  bf16* xb  = (bf16*)(ws + 0);          // 8 MiB  [4096,1024]
  bf16* wqb = (bf16*)(ws + 8388608);    // 2 MiB each
  bf16* wkb = (bf16*)(ws + 10485760);
  bf16* wvb = (bf16*)(ws + 12582912);
  bf16* wob = (bf16*)(ws + 14680064);
  bf16* qb  = (bf16*)(ws + 16777216);   // 8 MiB [B,L,H,HD]
  bf16* kb  = (bf16*)(ws + 25165824);
  bf16* vb  = (bf16*)(ws + 33554432);
  bf16* ab  = (bf16*)(ws + 41943040);   // attn out, 8 MiB; total 48 MiB
  (void)ws_size;

  cvt_x_kernel<<<16384, 256, 0, stream>>>(x, xb, NB * SEQ_L * DM);
  cvt_w_kernel<<<dim3(4096, 4), 256, 0, stream>>>(wq, wk, wv, wo, wqb, wkb, wvb, wob);
  qkv_gemm_kernel<<<dim3(32, 8, 3), 256, 0, stream>>>(xb, wqb, wkb, wvb, qb, kb, vb);
  rope_kernel<<<8192, 256, 0, stream>>>(qb, kb, freqs);
  attn_kernel<<<dim3(513, NH, NB), 256, 0, stream>>>(qb, kb, vb, ab);
  out_gemm_kernel<<<dim3(32, 8), 256, 0, stream>>>(ab, wob, out);
}

// Round 5
// 305.585 us; speedup vs baseline: 5.3989x; 1.1030x over previous
//
#include <hip/hip_runtime.h>
#include <math.h>

#define SEQ_L 2048
#define DM 1024
#define NH 16
#define HD 64
#define NB 2
#define KD 1024   // GEMM K
#define ND 1024   // GEMM N

typedef __bf16 bf16;
typedef __bf16 bf16x8 __attribute__((ext_vector_type(8)));
typedef __bf16 bf16x4 __attribute__((ext_vector_type(4)));
typedef float f32x4 __attribute__((ext_vector_type(4)));

// ---------------- conversions ----------------
__global__ void cvt_x_kernel(const float* __restrict__ in, bf16* __restrict__ out, int n) {
  int i = blockIdx.x * 256 + threadIdx.x;
  if (i < n) out[i] = (bf16)in[i];
}

__global__ void cvt_w_kernel(const float* __restrict__ w0, const float* __restrict__ w1,
                             const float* __restrict__ w2, const float* __restrict__ w3,
                             bf16* __restrict__ o0, bf16* __restrict__ o1,
                             bf16* __restrict__ o2, bf16* __restrict__ o3) {
  int i = blockIdx.x * 256 + threadIdx.x;
  const float* w; bf16* o;
  switch (blockIdx.y) {
    case 0: w = w0; o = o0; break;
    case 1: w = w1; o = o1; break;
    case 2: w = w2; o = o2; break;
    default: w = w3; o = o3; break;
  }
  o[i] = (bf16)w[i];
}

// ---------------- GEMM: C[m][n] = sum_k A[m][k] * W[n][k]  (B^T layout, m97 pattern) ----------------
__device__ inline void gld16(const bf16* g, bf16* l) {
  __builtin_amdgcn_global_load_lds((const __attribute__((address_space(1))) void*)g,
                                   (__attribute__((address_space(3))) void*)l, 16, 0, 0);
}

template <typename OutT>
__device__ inline void gemm_bt_body(const bf16* __restrict__ A, const bf16* __restrict__ W,
                                    OutT* __restrict__ C) {
  __shared__ __align__(16) bf16 As[128 * 32];
  __shared__ __align__(16) bf16 Bs[128 * 32];
  const int t = threadIdx.x;
  const int lane = t & 63;
  const int wave = t >> 6;
  const int wm = (wave >> 1) * 64;
  const int wn = (wave & 1) * 64;
  const int m0 = blockIdx.x * 128;
  const int n0 = blockIdx.y * 128;
  const int r = t >> 2;            // staging row 0..63
  const int ck = (t & 3) * 8;      // staging k-chunk (8 bf16 = 16B)
  const int l15 = lane & 15;
  const int koff = (lane >> 4) * 8;

  f32x4 acc[4][4] = {};

  for (int k0 = 0; k0 < KD; k0 += 32) {
    gld16(A + (size_t)(m0 + r) * KD + k0 + ck, As + t * 8);
    gld16(A + (size_t)(m0 + 64 + r) * KD + k0 + ck, As + 2048 + t * 8);
    gld16(W + (size_t)(n0 + r) * KD + k0 + ck, Bs + t * 8);
    gld16(W + (size_t)(n0 + 64 + r) * KD + k0 + ck, Bs + 2048 + t * 8);
    __syncthreads();
    bf16x8 af[4], bfr[4];
#pragma unroll
    for (int mt = 0; mt < 4; ++mt)
      af[mt] = *(const bf16x8*)(As + (wm + mt * 16 + l15) * 32 + koff);
#pragma unroll
    for (int nt = 0; nt < 4; ++nt)
      bfr[nt] = *(const bf16x8*)(Bs + (wn + nt * 16 + l15) * 32 + koff);
#pragma unroll
    for (int mt = 0; mt < 4; ++mt)
#pragma unroll
      for (int nt = 0; nt < 4; ++nt)
        acc[mt][nt] = __builtin_amdgcn_mfma_f32_16x16x32_bf16(af[mt], bfr[nt], acc[mt][nt], 0, 0, 0);
    __syncthreads();
  }
  // C/D layout: col = lane&15, row = (lane>>4)*4 + reg   [verified m89]
  const int colb = n0 + wn + l15;
  const int rowb = m0 + wm + (lane >> 4) * 4;
#pragma unroll
  for (int mt = 0; mt < 4; ++mt)
#pragma unroll
    for (int nt = 0; nt < 4; ++nt)
#pragma unroll
      for (int rr = 0; rr < 4; ++rr)
        C[(size_t)(rowb + mt * 16 + rr) * ND + colb + nt * 16] = (OutT)acc[mt][nt][rr];
}

__global__ __launch_bounds__(256, 2) void qkv_gemm_kernel(
    const bf16* __restrict__ xb, const bf16* __restrict__ wqb, const bf16* __restrict__ wkb,
    const bf16* __restrict__ wvb, bf16* __restrict__ qb, bf16* __restrict__ kb, bf16* __restrict__ vb) {
  const bf16* W = blockIdx.z == 0 ? wqb : blockIdx.z == 1 ? wkb : wvb;
  bf16* O = blockIdx.z == 0 ? qb : blockIdx.z == 1 ? kb : vb;
  gemm_bt_body<bf16>(xb, W, O);
}

__global__ __launch_bounds__(256, 2) void out_gemm_kernel(
    const bf16* __restrict__ ab, const bf16* __restrict__ wob, float* __restrict__ out) {
  gemm_bt_body<float>(ab, wob, out);
}

// ---------------- RoPE (in place on q,k; layout [B,L,H,HD]) ----------------
__global__ void rope_kernel(bf16* __restrict__ q, bf16* __restrict__ k, const float* __restrict__ freqs) {
  int idx = blockIdx.x * 256 + threadIdx.x;     // over B*L*NH*32 = 2097152 pairs
  int jj = idx & 31;
  int bl = idx >> 9;                            // b*SEQ_L + l
  int l = bl & (SEQ_L - 1);
  float ang = freqs[l * 32 + jj];
  float s, c;
  __sincosf(ang, &s, &c);     // max arg ~2047 rad; err ~2.5e-4 << bf16 noise
  size_t base = (size_t)idx * 2;
  float qre = (float)q[base], qim = (float)q[base + 1];
  q[base]     = (bf16)(qre * c - qim * s);
  q[base + 1] = (bf16)(qre * s + qim * c);
  float kre = (float)k[base], kim = (float)k[base + 1];
  k[base]     = (bf16)(kre * c - kim * s);
  k[base + 1] = (bf16)(kre * s + kim * c);
}

// ---------------- jax threefry2x32, key = (0, 42); partitionable random_bits ----------------
__device__ inline uint32_t rotl32(uint32_t v, int n) { return (v << n) | (v >> (32 - n)); }

__device__ inline void threefry(uint32_t x0, uint32_t x1, uint32_t* o0, uint32_t* o1) {
  const uint32_t ks0 = 0u, ks1 = 42u, ks2 = 0u ^ 42u ^ 0x1BD11BDAu;
  x0 += ks0; x1 += ks1;
#define TF_R(rr) { x0 += x1; x1 = rotl32(x1, rr); x1 ^= x0; }
  TF_R(13) TF_R(15) TF_R(26) TF_R(6)
  x0 += ks1; x1 += ks2 + 1u;
  TF_R(17) TF_R(29) TF_R(16) TF_R(24)
  x0 += ks2; x1 += ks0 + 2u;
  TF_R(13) TF_R(15) TF_R(26) TF_R(6)
  x0 += ks0; x1 += ks1 + 3u;
  TF_R(17) TF_R(29) TF_R(16) TF_R(24)
  x0 += ks1; x1 += ks2 + 4u;
  TF_R(13) TF_R(15) TF_R(26) TF_R(6)
  x0 += ks2; x1 += ks0 + 5u;
#undef TF_R
  *o0 = x0; *o1 = x1;
}

// jax_threefry_partitionable=True: counter (hi=0, lo=flat_idx), bits = o0 ^ o1.
__device__ inline int rand_col(int i, int s) {
  uint32_t o0, o1;
  threefry(0u, (uint32_t)(2 * i + s), &o0, &o1);
  uint32_t bits = o0 ^ o1;
  float u = __uint_as_float((bits >> 9) | 0x3f800000u) - 1.0f;
  return (int)floorf(u * (float)(i + 1));
}

// ---------------- column table: 12 ints per row (11 cols padded -1, + pad) ----------------
__global__ void build_cols_kernel(int* __restrict__ ctab) {
  const int i = blockIdx.x * 256 + threadIdx.x;   // 0..2047
  int cols[11]; int nc = 0;
  if (i >= 1) {
    int lo = i - 7; if (lo < 0) lo = 0;
    for (int j = lo; j <= i; ++j) cols[nc++] = j;
    if (lo > 0) cols[nc++] = 0;
#pragma unroll
    for (int s = 0; s < 2; ++s) {
      int rj = rand_col(i, s);
      bool dup = false;
      for (int c2 = 0; c2 < nc; ++c2) dup |= (cols[c2] == rj);
      if (!dup) cols[nc++] = rj;
    }
  }
  for (int c2 = nc; c2 < 11; ++c2) cols[c2] = -1;
#pragma unroll
  for (int c2 = 0; c2 < 11; ++c2) ctab[i * 12 + c2] = cols[c2];
  ctab[i * 12 + 11] = nc;
}

// ---------------- attention ----------------
// grid (2047+16, NB), 256 threads.
//  bx < 2047 : row i = bx+1, ALL 16 heads. wave w -> heads 4w..4w+3;
//              16-lane team per head, lane holds 4 dims (8B vec loads; k/v row
//              access = one contiguous 512B wave-load). 4-level team shfl reduce.
//  bx >= 2047: dense row 0 for head h = bx-2047 (block softmax over 2048 cols).
__global__ __launch_bounds__(256) void attn_kernel(const bf16* __restrict__ q, const bf16* __restrict__ k,
                                                   const bf16* __restrict__ v, bf16* __restrict__ o,
                                                   const int* __restrict__ ctab) {
  const int b = blockIdx.y;
  const int t = threadIdx.x;
  const int lane = t & 63;
  const int w = t >> 6;

  __shared__ float pbuf[SEQ_L];
  __shared__ float redm[4], redz[4];
  __shared__ float part[4][64];

  if (blockIdx.x < 2047) {
    const int i = blockIdx.x + 1;
    const int team = lane >> 4;           // 0..3
    const int tl = lane & 15;             // lane in team
    const int h = w * 4 + team;           // head
    const int d0 = tl * 4;                // 4 dims per lane
    const size_t rowstride = DM;          // elements per (b,l) row
    const size_t base = (size_t)b * SEQ_L * DM + (size_t)h * HD + d0;

    // column list (uniform per block): 3 x int4
    const int4* cp = (const int4*)(ctab + i * 12);
    int4 ca = cp[0], cb = cp[1], cc = cp[2];
    int cols[11] = {ca.x, ca.y, ca.z, ca.w, cb.x, cb.y, cb.z, cb.w, cc.x, cc.y, cc.z};

    bf16x4 qv = *(const bf16x4*)(q + base + (size_t)i * rowstride);
    float q0 = (float)qv[0], q1 = (float)qv[1], q2 = (float)qv[2], q3 = (float)qv[3];

    float sv[11];
#pragma unroll
    for (int c = 0; c < 11; ++c) {
      int cj = cols[c] < 0 ? 0 : cols[c];
      bf16x4 kv = *(const bf16x4*)(k + base + (size_t)cj * rowstride);
      sv[c] = q0 * (float)kv[0] + q1 * (float)kv[1] + q2 * (float)kv[2] + q3 * (float)kv[3];
    }
#pragma unroll
    for (int c = 0; c < 11; ++c) {
#pragma unroll
      for (int off = 1; off < 16; off <<= 1) sv[c] += __shfl_xor(sv[c], off);
      sv[c] = cols[c] < 0 ? -1e30f : sv[c] * 0.125f;
    }
    float m = -1e30f;
#pragma unroll
    for (int c = 0; c < 11; ++c) m = fmaxf(m, sv[c]);
    float z = 0.f;
#pragma unroll
    for (int c = 0; c < 11; ++c) { sv[c] = __expf(sv[c] - m); z += sv[c]; }
    const float inv = 1.f / z;

    float o0 = 0.f, o1 = 0.f, o2 = 0.f, o3 = 0.f;
#pragma unroll
    for (int c = 0; c < 11; ++c) {
      int cj = cols[c] < 0 ? 0 : cols[c];
      bf16x4 vv = *(const bf16x4*)(v + base + (size_t)cj * rowstride);
      o0 += sv[c] * (float)vv[0];
      o1 += sv[c] * (float)vv[1];
      o2 += sv[c] * (float)vv[2];
      o3 += sv[c] * (float)vv[3];
    }
    bf16x4 ov;
    ov[0] = (bf16)(o0 * inv); ov[1] = (bf16)(o1 * inv);
    ov[2] = (bf16)(o2 * inv); ov[3] = (bf16)(o3 * inv);
    *(bf16x4*)(o + base + (size_t)i * rowstride) = ov;
    return;
  }

  // ---- dense row 0, head h ----
  const int h = blockIdx.x - 2047;
  const size_t hb = (size_t)b * SEQ_L * DM + (size_t)h * HD;

  bf16x8 qv8[8];
#pragma unroll
  for (int c = 0; c < 8; ++c) qv8[c] = *(const bf16x8*)(q + hb + c * 8);

  float mloc = -1e30f;
  for (int j = t; j < SEQ_L; j += 256) {
    float acc = 0.f;
#pragma unroll
    for (int c = 0; c < 8; ++c) {
      bf16x8 kv = *(const bf16x8*)(k + hb + (size_t)j * DM + c * 8);
#pragma unroll
      for (int e = 0; e < 8; ++e) acc += (float)qv8[c][e] * (float)kv[e];
    }
    float s = acc * 0.125f;
    pbuf[j] = s;
    mloc = fmaxf(mloc, s);
  }
#pragma unroll
  for (int off = 32; off > 0; off >>= 1) mloc = fmaxf(mloc, __shfl_xor(mloc, off));
  if (lane == 0) redm[w] = mloc;
  __syncthreads();
  const float m = fmaxf(fmaxf(redm[0], redm[1]), fmaxf(redm[2], redm[3]));

  float zloc = 0.f;
  for (int j = t; j < SEQ_L; j += 256) {
    float e = __expf(pbuf[j] - m);
    pbuf[j] = e;
    zloc += e;
  }
#pragma unroll
  for (int off = 32; off > 0; off >>= 1) zloc += __shfl_xor(zloc, off);
  if (lane == 0) redz[w] = zloc;
  __syncthreads();
  const float z = redz[0] + redz[1] + redz[2] + redz[3];

  float oa = 0.f;
  for (int j = w; j < SEQ_L; j += 4)
    oa += pbuf[j] * (float)v[hb + (size_t)j * DM + lane];
  part[w][lane] = oa;
  __syncthreads();
  if (t < 64)
    o[hb + t] = (bf16)((part[0][t] + part[1][t] + part[2][t] + part[3][t]) / z);
}

// ---------------- launch ----------------
extern "C" void kernel_launch(void* const* d_in, const int* in_sizes, int n_in,
                              void* d_out, int out_size, void* d_ws, size_t ws_size,
                              hipStream_t stream) {
  const float* x     = (const float*)d_in[0];
  const float* freqs = (const float*)d_in[1];
  const float* wq    = (const float*)d_in[2];
  const float* wk    = (const float*)d_in[3];
  const float* wv    = (const float*)d_in[4];
  const float* wo    = (const float*)d_in[5];
  float* out = (float*)d_out;

  char* ws = (char*)d_ws;
  bf16* xb  = (bf16*)(ws + 0);          // 8 MiB [4096,1024]; dead after qkv -> reused for ctab
  bf16* wqb = (bf16*)(ws + 8388608);    // 2 MiB each
  bf16* wkb = (bf16*)(ws + 10485760);
  bf16* wvb = (bf16*)(ws + 12582912);
  bf16* wob = (bf16*)(ws + 14680064);
  bf16* qb  = (bf16*)(ws + 16777216);   // 8 MiB [B,L,H,HD]
  bf16* kb  = (bf16*)(ws + 25165824);
  bf16* vb  = (bf16*)(ws + 33554432);
  bf16* ab  = (bf16*)(ws + 41943040);   // attn out, 8 MiB; total 48 MiB
  int*  ctab = (int*)(ws + 0);          // aliases xb; written after qkv_gemm
  (void)ws_size;

  cvt_x_kernel<<<16384, 256, 0, stream>>>(x, xb, NB * SEQ_L * DM);
  cvt_w_kernel<<<dim3(4096, 4), 256, 0, stream>>>(wq, wk, wv, wo, wqb, wkb, wvb, wob);
  qkv_gemm_kernel<<<dim3(32, 8, 3), 256, 0, stream>>>(xb, wqb, wkb, wvb, qb, kb, vb);
  build_cols_kernel<<<8, 256, 0, stream>>>(ctab);   // after qkv: reuses xb space
  rope_kernel<<<8192, 256, 0, stream>>>(qb, kb, freqs);
  attn_kernel<<<dim3(2047 + 16, NB), 256, 0, stream>>>(qb, kb, vb, ab, ctab);
  out_gemm_kernel<<<dim3(32, 8), 256, 0, stream>>>(ab, wob, out);
}

// Round 6
// 185.988 us; speedup vs baseline: 8.8706x; 1.6430x over previous
//
#include <hip/hip_runtime.h>
#include <math.h>

#define SEQ_L 2048
#define DM 1024
#define NH 16
#define HD 64
#define NB 2
#define KD 1024   // GEMM K
#define ND 1024   // GEMM N

typedef __bf16 bf16;
typedef __bf16 bf16x8 __attribute__((ext_vector_type(8)));
typedef __bf16 bf16x4 __attribute__((ext_vector_type(4)));
typedef float f32x4 __attribute__((ext_vector_type(4)));

// ---------------- conversions ----------------
__global__ void cvt_x_kernel(const float* __restrict__ in, bf16* __restrict__ out, int n) {
  int i = blockIdx.x * 256 + threadIdx.x;
  if (i < n) out[i] = (bf16)in[i];
}

__global__ void cvt_w_kernel(const float* __restrict__ w0, const float* __restrict__ w1,
                             const float* __restrict__ w2, const float* __restrict__ w3,
                             bf16* __restrict__ o0, bf16* __restrict__ o1,
                             bf16* __restrict__ o2, bf16* __restrict__ o3) {
  int i = blockIdx.x * 256 + threadIdx.x;
  const float* w; bf16* o;
  switch (blockIdx.y) {
    case 0: w = w0; o = o0; break;
    case 1: w = w1; o = o1; break;
    case 2: w = w2; o = o2; break;
    default: w = w3; o = o3; break;
  }
  o[i] = (bf16)w[i];
}

// ---------------- GEMM: C[m][n] = sum_k A[m][k] * W[n][k]  (B^T layout, m97 pattern) ----------------
__device__ inline void gld16(const bf16* g, bf16* l) {
  __builtin_amdgcn_global_load_lds((const __attribute__((address_space(1))) void*)g,
                                   (__attribute__((address_space(3))) void*)l, 16, 0, 0);
}

template <typename OutT>
__device__ inline void gemm_bt_body(const bf16* __restrict__ A, const bf16* __restrict__ W,
                                    OutT* __restrict__ C) {
  __shared__ __align__(16) bf16 As[128 * 32];
  __shared__ __align__(16) bf16 Bs[128 * 32];
  const int t = threadIdx.x;
  const int lane = t & 63;
  const int wave = t >> 6;
  const int wm = (wave >> 1) * 64;
  const int wn = (wave & 1) * 64;
  const int m0 = blockIdx.x * 128;
  const int n0 = blockIdx.y * 128;
  const int r = t >> 2;            // staging row 0..63
  const int ck = (t & 3) * 8;      // staging k-chunk (8 bf16 = 16B)
  const int l15 = lane & 15;
  const int koff = (lane >> 4) * 8;

  f32x4 acc[4][4] = {};

  for (int k0 = 0; k0 < KD; k0 += 32) {
    gld16(A + (size_t)(m0 + r) * KD + k0 + ck, As + t * 8);
    gld16(A + (size_t)(m0 + 64 + r) * KD + k0 + ck, As + 2048 + t * 8);
    gld16(W + (size_t)(n0 + r) * KD + k0 + ck, Bs + t * 8);
    gld16(W + (size_t)(n0 + 64 + r) * KD + k0 + ck, Bs + 2048 + t * 8);
    __syncthreads();
    bf16x8 af[4], bfr[4];
#pragma unroll
    for (int mt = 0; mt < 4; ++mt)
      af[mt] = *(const bf16x8*)(As + (wm + mt * 16 + l15) * 32 + koff);
#pragma unroll
    for (int nt = 0; nt < 4; ++nt)
      bfr[nt] = *(const bf16x8*)(Bs + (wn + nt * 16 + l15) * 32 + koff);
#pragma unroll
    for (int mt = 0; mt < 4; ++mt)
#pragma unroll
      for (int nt = 0; nt < 4; ++nt)
        acc[mt][nt] = __builtin_amdgcn_mfma_f32_16x16x32_bf16(af[mt], bfr[nt], acc[mt][nt], 0, 0, 0);
    __syncthreads();
  }
  // C/D layout: col = lane&15, row = (lane>>4)*4 + reg   [verified m89]
  const int colb = n0 + wn + l15;
  const int rowb = m0 + wm + (lane >> 4) * 4;
#pragma unroll
  for (int mt = 0; mt < 4; ++mt)
#pragma unroll
    for (int nt = 0; nt < 4; ++nt)
#pragma unroll
      for (int rr = 0; rr < 4; ++rr)
        C[(size_t)(rowb + mt * 16 + rr) * ND + colb + nt * 16] = (OutT)acc[mt][nt][rr];
}

__global__ __launch_bounds__(256, 2) void qkv_gemm_kernel(
    const bf16* __restrict__ xb, const bf16* __restrict__ wqb, const bf16* __restrict__ wkb,
    const bf16* __restrict__ wvb, bf16* __restrict__ qb, bf16* __restrict__ kb, bf16* __restrict__ vb) {
  const bf16* W = blockIdx.z == 0 ? wqb : blockIdx.z == 1 ? wkb : wvb;
  bf16* O = blockIdx.z == 0 ? qb : blockIdx.z == 1 ? kb : vb;
  gemm_bt_body<bf16>(xb, W, O);
}

__global__ __launch_bounds__(256, 2) void out_gemm_kernel(
    const bf16* __restrict__ ab, const bf16* __restrict__ wob, float* __restrict__ out) {
  gemm_bt_body<float>(ab, wob, out);
}

// ---------------- RoPE (in place on q,k; layout [B,L,H,HD]) ----------------
__global__ void rope_kernel(bf16* __restrict__ q, bf16* __restrict__ k, const float* __restrict__ freqs) {
  int idx = blockIdx.x * 256 + threadIdx.x;     // over B*L*NH*32 = 2097152 pairs
  int jj = idx & 31;
  int bl = idx >> 9;                            // b*SEQ_L + l
  int l = bl & (SEQ_L - 1);
  float ang = freqs[l * 32 + jj];
  float s, c;
  __sincosf(ang, &s, &c);     // max arg ~2047 rad; err ~2.5e-4 << bf16 noise
  size_t base = (size_t)idx * 2;
  float qre = (float)q[base], qim = (float)q[base + 1];
  q[base]     = (bf16)(qre * c - qim * s);
  q[base + 1] = (bf16)(qre * s + qim * c);
  float kre = (float)k[base], kim = (float)k[base + 1];
  k[base]     = (bf16)(kre * c - kim * s);
  k[base + 1] = (bf16)(kre * s + kim * c);
}

// ---------------- jax threefry2x32, key = (0, 42); partitionable random_bits ----------------
__device__ inline uint32_t rotl32(uint32_t v, int n) { return (v << n) | (v >> (32 - n)); }

__device__ inline void threefry(uint32_t x0, uint32_t x1, uint32_t* o0, uint32_t* o1) {
  const uint32_t ks0 = 0u, ks1 = 42u, ks2 = 0u ^ 42u ^ 0x1BD11BDAu;
  x0 += ks0; x1 += ks1;
#define TF_R(rr) { x0 += x1; x1 = rotl32(x1, rr); x1 ^= x0; }
  TF_R(13) TF_R(15) TF_R(26) TF_R(6)
  x0 += ks1; x1 += ks2 + 1u;
  TF_R(17) TF_R(29) TF_R(16) TF_R(24)
  x0 += ks2; x1 += ks0 + 2u;
  TF_R(13) TF_R(15) TF_R(26) TF_R(6)
  x0 += ks0; x1 += ks1 + 3u;
  TF_R(17) TF_R(29) TF_R(16) TF_R(24)
  x0 += ks1; x1 += ks2 + 4u;
  TF_R(13) TF_R(15) TF_R(26) TF_R(6)
  x0 += ks2; x1 += ks0 + 5u;
#undef TF_R
  *o0 = x0; *o1 = x1;
}

// jax_threefry_partitionable=True: counter (hi=0, lo=flat_idx), bits = o0 ^ o1.
__device__ inline int rand_col(int i, int s) {
  uint32_t o0, o1;
  threefry(0u, (uint32_t)(2 * i + s), &o0, &o1);
  uint32_t bits = o0 ^ o1;
  float u = __uint_as_float((bits >> 9) | 0x3f800000u) - 1.0f;
  return (int)floorf(u * (float)(i + 1));
}

// ---------------- column table: 12 ints per row (11 cols padded -1, + count) ----------------
__global__ void build_cols_kernel(int* __restrict__ ctab) {
  const int i = blockIdx.x * 256 + threadIdx.x;   // 0..2047
  int cols[11]; int nc = 0;
  if (i >= 1) {
    int lo = i - 7; if (lo < 0) lo = 0;
    for (int j = lo; j <= i; ++j) cols[nc++] = j;
    if (lo > 0) cols[nc++] = 0;
#pragma unroll
    for (int s = 0; s < 2; ++s) {
      int rj = rand_col(i, s);
      bool dup = false;
      for (int c2 = 0; c2 < nc; ++c2) dup |= (cols[c2] == rj);
      if (!dup) cols[nc++] = rj;
    }
  }
  for (int c2 = nc; c2 < 11; ++c2) cols[c2] = -1;
#pragma unroll
  for (int c2 = 0; c2 < 11; ++c2) ctab[i * 12 + c2] = cols[c2];
  ctab[i * 12 + 11] = nc;
}

// ---------------- attention ----------------
// grid (1280, 1), 256 threads.
//  bx < 1024 : sparse rows. b = bx>>9; t = bx&511; tile XCD-swizzled; wave w handles
//              row i = tile*4+1+w for ALL 16 heads: lane covers dims lane*16..+15
//              (head = lane>>2 folds away) -> every k/v/q/o access is one contiguous
//              2KB wave-load. 2-shfl team reduction for scores.
//  bx >= 1024: row-0 partials: idx=bx-1024 -> (b, h, chunk c of 256 cols); block
//              computes chunk max/sum/weighted-V into pm/pz/pv; combined later.
__global__ __launch_bounds__(256) void attn_kernel(const bf16* __restrict__ q, const bf16* __restrict__ k,
                                                   const bf16* __restrict__ v, bf16* __restrict__ o,
                                                   const int* __restrict__ ctab,
                                                   float* __restrict__ pm, float* __restrict__ pz,
                                                   float* __restrict__ pv) {
  const int t = threadIdx.x;
  const int lane = t & 63;
  const int w = t >> 6;

  __shared__ float sbuf[256];
  __shared__ float redm[4], redz[4];
  __shared__ float part[4][64];

  if (blockIdx.x < 1024) {
    const int b = blockIdx.x >> 9;
    const int tt = blockIdx.x & 511;
    const int tile = ((tt & 7) << 6) + (tt >> 3);   // XCD swizzle: 64 consecutive tiles/XCD
    const int i = tile * 4 + 1 + w;
    if (i >= SEQ_L) return;   // wave-uniform
    const size_t bb = (size_t)b * SEQ_L * DM;
    const int eo = lane * 16;                       // dim offset within 1024-wide row

    const bf16* qrow = q + bb + (size_t)i * DM + eo;
    bf16x8 qv0 = *(const bf16x8*)(qrow);
    bf16x8 qv1 = *(const bf16x8*)(qrow + 8);

    const int4* cp = (const int4*)(ctab + i * 12);
    int4 ca = cp[0], cb = cp[1], cc = cp[2];
    int cols[11] = {ca.x, ca.y, ca.z, ca.w, cb.x, cb.y, cb.z, cb.w, cc.x, cc.y, cc.z};

    float sv[11];
#pragma unroll
    for (int c = 0; c < 11; ++c) {
      int cj = cols[c] < 0 ? 0 : cols[c];
      const bf16* krow = k + bb + (size_t)cj * DM + eo;
      bf16x8 kv0 = *(const bf16x8*)(krow);
      bf16x8 kv1 = *(const bf16x8*)(krow + 8);
      float acc = 0.f;
#pragma unroll
      for (int e = 0; e < 8; ++e)
        acc += (float)qv0[e] * (float)kv0[e] + (float)qv1[e] * (float)kv1[e];
      sv[c] = acc;
    }
#pragma unroll
    for (int c = 0; c < 11; ++c) {
      sv[c] += __shfl_xor(sv[c], 1);    // reduce over 4-lane team (one head)
      sv[c] += __shfl_xor(sv[c], 2);
      sv[c] = cols[c] < 0 ? -1e30f : sv[c] * 0.125f;
    }
    float m = -1e30f;
#pragma unroll
    for (int c = 0; c < 11; ++c) m = fmaxf(m, sv[c]);
    float z = 0.f;
#pragma unroll
    for (int c = 0; c < 11; ++c) { sv[c] = __expf(sv[c] - m); z += sv[c]; }
    const float inv = 1.f / z;

    float oa[16] = {};
#pragma unroll
    for (int c = 0; c < 11; ++c) {
      int cj = cols[c] < 0 ? 0 : cols[c];
      const bf16* vrow = v + bb + (size_t)cj * DM + eo;
      bf16x8 vv0 = *(const bf16x8*)(vrow);
      bf16x8 vv1 = *(const bf16x8*)(vrow + 8);
#pragma unroll
      for (int e = 0; e < 8; ++e) {
        oa[e]     += sv[c] * (float)vv0[e];
        oa[8 + e] += sv[c] * (float)vv1[e];
      }
    }
    bf16x8 ov0, ov1;
#pragma unroll
    for (int e = 0; e < 8; ++e) {
      ov0[e] = (bf16)(oa[e] * inv);
      ov1[e] = (bf16)(oa[8 + e] * inv);
    }
    bf16* orow = o + bb + (size_t)i * DM + eo;
    *(bf16x8*)(orow) = ov0;
    *(bf16x8*)(orow + 8) = ov1;
    return;
  }

  // ---- row-0 partial: (b, h, chunk of 256 cols) ----
  const int idx = blockIdx.x - 1024;    // 0..255
  const int b = idx >> 7;
  const int rem = idx & 127;
  const int h = rem >> 3;
  const int c = rem & 7;
  const size_t hb = (size_t)b * SEQ_L * DM + (size_t)h * HD;
  const int j = c * 256 + t;            // this thread's column

  bf16x8 qv8[8];
#pragma unroll
  for (int cc = 0; cc < 8; ++cc) qv8[cc] = *(const bf16x8*)(q + hb + cc * 8);

  float acc = 0.f;
#pragma unroll
  for (int cc = 0; cc < 8; ++cc) {
    bf16x8 kv = *(const bf16x8*)(k + hb + (size_t)j * DM + cc * 8);
#pragma unroll
    for (int e = 0; e < 8; ++e) acc += (float)qv8[cc][e] * (float)kv[e];
  }
  float s = acc * 0.125f;
  float mloc = s;
#pragma unroll
  for (int off = 32; off > 0; off >>= 1) mloc = fmaxf(mloc, __shfl_xor(mloc, off));
  if (lane == 0) redm[w] = mloc;
  __syncthreads();
  const float m = fmaxf(fmaxf(redm[0], redm[1]), fmaxf(redm[2], redm[3]));

  float e = __expf(s - m);
  sbuf[t] = e;
  float zloc = e;
#pragma unroll
  for (int off = 32; off > 0; off >>= 1) zloc += __shfl_xor(zloc, off);
  if (lane == 0) redz[w] = zloc;
  __syncthreads();
  const float zc = redz[0] + redz[1] + redz[2] + redz[3];

  float oa = 0.f;
  for (int jj = w; jj < 256; jj += 4)
    oa += sbuf[jj] * (float)v[hb + (size_t)(c * 256 + jj) * DM + lane];
  part[w][lane] = oa;
  __syncthreads();
  if (t < 64) pv[idx * 64 + t] = part[0][t] + part[1][t] + part[2][t] + part[3][t];
  if (t == 0) { pm[idx] = m; pz[idx] = zc; }
}

// combine row-0 partials: one block per (b,h), 64 threads (lane = dim)
__global__ __launch_bounds__(64) void row0_combine_kernel(const float* __restrict__ pm,
                                                          const float* __restrict__ pz,
                                                          const float* __restrict__ pv,
                                                          bf16* __restrict__ o) {
  const int bh = blockIdx.x;            // 0..31: b = bh>>4, h = bh&15
  const int b = bh >> 4, h = bh & 15;
  const int d = threadIdx.x;
  const int base = bh * 8;
  float M = -1e30f;
#pragma unroll
  for (int c = 0; c < 8; ++c) M = fmaxf(M, pm[base + c]);
  float Z = 0.f, od = 0.f;
#pragma unroll
  for (int c = 0; c < 8; ++c) {
    float sc = __expf(pm[base + c] - M);
    Z += pz[base + c] * sc;
    od += pv[(base + c) * 64 + d] * sc;
  }
  o[(size_t)b * SEQ_L * DM + (size_t)h * HD + d] = (bf16)(od / Z);
}

// ---------------- launch ----------------
extern "C" void kernel_launch(void* const* d_in, const int* in_sizes, int n_in,
                              void* d_out, int out_size, void* d_ws, size_t ws_size,
                              hipStream_t stream) {
  const float* x     = (const float*)d_in[0];
  const float* freqs = (const float*)d_in[1];
  const float* wq    = (const float*)d_in[2];
  const float* wk    = (const float*)d_in[3];
  const float* wv    = (const float*)d_in[4];
  const float* wo    = (const float*)d_in[5];
  float* out = (float*)d_out;

  char* ws = (char*)d_ws;
  bf16* xb  = (bf16*)(ws + 0);          // 8 MiB [4096,1024]; dead after qkv -> reused
  bf16* wqb = (bf16*)(ws + 8388608);    // 2 MiB each
  bf16* wkb = (bf16*)(ws + 10485760);
  bf16* wvb = (bf16*)(ws + 12582912);
  bf16* wob = (bf16*)(ws + 14680064);
  bf16* qb  = (bf16*)(ws + 16777216);   // 8 MiB [B,L,H,HD]
  bf16* kb  = (bf16*)(ws + 25165824);
  bf16* vb  = (bf16*)(ws + 33554432);
  bf16* ab  = (bf16*)(ws + 41943040);   // attn out, 8 MiB; total 48 MiB
  int*   ctab = (int*)(ws + 0);         // aliases xb (dead after qkv): 96 KB
  float* pm   = (float*)(ws + 4194304); // row-0 partials, also inside dead xb region
  float* pz   = (float*)(ws + 4194304 + 1024);
  float* pv   = (float*)(ws + 4194304 + 2048);  // 64 KB
  (void)ws_size;

  cvt_x_kernel<<<16384, 256, 0, stream>>>(x, xb, NB * SEQ_L * DM);
  cvt_w_kernel<<<dim3(4096, 4), 256, 0, stream>>>(wq, wk, wv, wo, wqb, wkb, wvb, wob);
  qkv_gemm_kernel<<<dim3(32, 8, 3), 256, 0, stream>>>(xb, wqb, wkb, wvb, qb, kb, vb);
  build_cols_kernel<<<8, 256, 0, stream>>>(ctab);   // after qkv: reuses xb space
  rope_kernel<<<8192, 256, 0, stream>>>(qb, kb, freqs);
  attn_kernel<<<dim3(1280, 1), 256, 0, stream>>>(qb, kb, vb, ab, ctab, pm, pz, pv);
  row0_combine_kernel<<<32, 64, 0, stream>>>(pm, pz, pv, ab);
  out_gemm_kernel<<<dim3(32, 8), 256, 0, stream>>>(ab, wob, out);
}

// Round 7
// 175.836 us; speedup vs baseline: 9.3827x; 1.0577x over previous
//
#include <hip/hip_runtime.h>
#include <math.h>

#define SEQ_L 2048
#define DM 1024
#define NH 16
#define HD 64
#define NB 2
#define KD 1024   // GEMM K
#define ND 1024   // GEMM N

typedef __bf16 bf16;
typedef __bf16 bf16x8 __attribute__((ext_vector_type(8)));
typedef __bf16 bf16x4 __attribute__((ext_vector_type(4)));
typedef float f32x4 __attribute__((ext_vector_type(4)));

// ---------------- jax threefry2x32, key = (0, 42); partitionable random_bits ----------------
__device__ inline uint32_t rotl32(uint32_t v, int n) { return (v << n) | (v >> (32 - n)); }

__device__ inline void threefry(uint32_t x0, uint32_t x1, uint32_t* o0, uint32_t* o1) {
  const uint32_t ks0 = 0u, ks1 = 42u, ks2 = 0u ^ 42u ^ 0x1BD11BDAu;
  x0 += ks0; x1 += ks1;
#define TF_R(rr) { x0 += x1; x1 = rotl32(x1, rr); x1 ^= x0; }
  TF_R(13) TF_R(15) TF_R(26) TF_R(6)
  x0 += ks1; x1 += ks2 + 1u;
  TF_R(17) TF_R(29) TF_R(16) TF_R(24)
  x0 += ks2; x1 += ks0 + 2u;
  TF_R(13) TF_R(15) TF_R(26) TF_R(6)
  x0 += ks0; x1 += ks1 + 3u;
  TF_R(17) TF_R(29) TF_R(16) TF_R(24)
  x0 += ks1; x1 += ks2 + 4u;
  TF_R(13) TF_R(15) TF_R(26) TF_R(6)
  x0 += ks2; x1 += ks0 + 5u;
#undef TF_R
  *o0 = x0; *o1 = x1;
}

// jax_threefry_partitionable=True: counter (hi=0, lo=flat_idx), bits = o0 ^ o1.
__device__ inline int rand_col(int i, int s) {
  uint32_t o0, o1;
  threefry(0u, (uint32_t)(2 * i + s), &o0, &o1);
  uint32_t bits = o0 ^ o1;
  float u = __uint_as_float((bits >> 9) | 0x3f800000u) - 1.0f;
  return (int)floorf(u * (float)(i + 1));
}

// ---------------- prep: all f32->bf16 conversions (vectorized) + column table ----------------
// grid (8200, 1), 256 thr:
//   bx <  4096 : x  (4M elems, float4->bf16x4)
//   4096..8191 : weights (4 x 1M elems)
//   bx >= 8192 : build ctab rows
__global__ void prep_kernel(const float* __restrict__ x,
                            const float* __restrict__ w0, const float* __restrict__ w1,
                            const float* __restrict__ w2, const float* __restrict__ w3,
                            bf16* __restrict__ xb,
                            bf16* __restrict__ o0, bf16* __restrict__ o1,
                            bf16* __restrict__ o2, bf16* __restrict__ o3,
                            int* __restrict__ ctab) {
  const int bx = blockIdx.x;
  const int t = threadIdx.x;
  if (bx < 8192) {
    const float* src;
    bf16* dst;
    int idx;
    if (bx < 4096) { src = x; dst = xb; idx = bx * 256 + t; }
    else {
      int widx = bx - 4096;
      int wsel = widx >> 10;
      switch (wsel) {
        case 0: src = w0; dst = o0; break;
        case 1: src = w1; dst = o1; break;
        case 2: src = w2; dst = o2; break;
        default: src = w3; dst = o3; break;
      }
      idx = (widx & 1023) * 256 + t;
    }
    float4 vv = ((const float4*)src)[idx];
    bf16x4 ov;
    ov[0] = (bf16)vv.x; ov[1] = (bf16)vv.y; ov[2] = (bf16)vv.z; ov[3] = (bf16)vv.w;
    *(bf16x4*)(dst + (size_t)idx * 4) = ov;
    return;
  }
  // column table
  const int i = (bx - 8192) * 256 + t;    // 0..2047
  int cols[11]; int nc = 0;
  if (i >= 1) {
    int lo = i - 7; if (lo < 0) lo = 0;
    for (int j = lo; j <= i; ++j) cols[nc++] = j;
    if (lo > 0) cols[nc++] = 0;
#pragma unroll
    for (int s = 0; s < 2; ++s) {
      int rj = rand_col(i, s);
      bool dup = false;
      for (int c2 = 0; c2 < nc; ++c2) dup |= (cols[c2] == rj);
      if (!dup) cols[nc++] = rj;
    }
  }
  for (int c2 = nc; c2 < 11; ++c2) cols[c2] = -1;
#pragma unroll
  for (int c2 = 0; c2 < 11; ++c2) ctab[i * 12 + c2] = cols[c2];
  ctab[i * 12 + 11] = nc;
}

// ---------------- GEMM: C[m][n] = sum_k A[m][k] * W[n][k]  (B^T layout, m97 pattern) --------
__device__ inline void gld16(const bf16* g, bf16* l) {
  __builtin_amdgcn_global_load_lds((const __attribute__((address_space(1))) void*)g,
                                   (__attribute__((address_space(3))) void*)l, 16, 0, 0);
}

// 128x128 tile; optional fused RoPE epilogue (rope!=nullptr): rotates (even,odd)
// column pairs with angle freqs[(row & 2047)*32 + ((col&63)>>1)] via lane-pair shfl.
template <typename OutT>
__device__ inline void gemm_bt_body(const bf16* __restrict__ A, const bf16* __restrict__ W,
                                    OutT* __restrict__ C, const float* __restrict__ rope) {
  __shared__ __align__(16) bf16 As[128 * 32];
  __shared__ __align__(16) bf16 Bs[128 * 32];
  const int t = threadIdx.x;
  const int lane = t & 63;
  const int wave = t >> 6;
  const int wm = (wave >> 1) * 64;
  const int wn = (wave & 1) * 64;
  const int m0 = blockIdx.x * 128;
  const int n0 = blockIdx.y * 128;
  const int r = t >> 2;
  const int ck = (t & 3) * 8;
  const int l15 = lane & 15;
  const int koff = (lane >> 4) * 8;

  f32x4 acc[4][4] = {};

  for (int k0 = 0; k0 < KD; k0 += 32) {
    gld16(A + (size_t)(m0 + r) * KD + k0 + ck, As + t * 8);
    gld16(A + (size_t)(m0 + 64 + r) * KD + k0 + ck, As + 2048 + t * 8);
    gld16(W + (size_t)(n0 + r) * KD + k0 + ck, Bs + t * 8);
    gld16(W + (size_t)(n0 + 64 + r) * KD + k0 + ck, Bs + 2048 + t * 8);
    __syncthreads();
    bf16x8 af[4], bfr[4];
#pragma unroll
    for (int mt = 0; mt < 4; ++mt)
      af[mt] = *(const bf16x8*)(As + (wm + mt * 16 + l15) * 32 + koff);
#pragma unroll
    for (int nt = 0; nt < 4; ++nt)
      bfr[nt] = *(const bf16x8*)(Bs + (wn + nt * 16 + l15) * 32 + koff);
#pragma unroll
    for (int mt = 0; mt < 4; ++mt)
#pragma unroll
      for (int nt = 0; nt < 4; ++nt)
        acc[mt][nt] = __builtin_amdgcn_mfma_f32_16x16x32_bf16(af[mt], bfr[nt], acc[mt][nt], 0, 0, 0);
    __syncthreads();
  }
  // C/D layout: col = lane&15, row = (lane>>4)*4 + reg   [verified m89]
  const int colb = n0 + wn + l15;
  const int rowb = m0 + wm + (lane >> 4) * 4;
  const int odd = l15 & 1;
#pragma unroll
  for (int mt = 0; mt < 4; ++mt)
#pragma unroll
    for (int nt = 0; nt < 4; ++nt) {
      const int col = colb + nt * 16;
      const int jj = (col & 63) >> 1;
#pragma unroll
      for (int rr = 0; rr < 4; ++rr) {
        float val = acc[mt][nt][rr];
        if (rope) {
          const int row = rowb + mt * 16 + rr;
          const int l = row & (SEQ_L - 1);
          float s, c;
          __sincosf(rope[l * 32 + jj], &s, &c);
          float partner = __shfl_xor(val, 1);
          val = odd ? val * c + partner * s : val * c - partner * s;
        }
        C[(size_t)(rowb + mt * 16 + rr) * ND + colb + nt * 16] = (OutT)val;
      }
    }
}

__global__ __launch_bounds__(256, 2) void qkv_gemm_kernel(
    const bf16* __restrict__ xb, const bf16* __restrict__ wqb, const bf16* __restrict__ wkb,
    const bf16* __restrict__ wvb, bf16* __restrict__ qb, bf16* __restrict__ kb, bf16* __restrict__ vb,
    const float* __restrict__ freqs) {
  const bf16* W = blockIdx.z == 0 ? wqb : blockIdx.z == 1 ? wkb : wvb;
  bf16* O = blockIdx.z == 0 ? qb : blockIdx.z == 1 ? kb : vb;
  const float* fr = blockIdx.z < 2 ? freqs : nullptr;   // rope on q,k only
  gemm_bt_body<bf16>(xb, W, O, fr);
}

// ---- out-projection GEMM: 64x128 tile, grid (64,8) = 512 blocks = 2 blocks/CU ----
__global__ __launch_bounds__(256, 2) void out_gemm_kernel(
    const bf16* __restrict__ ab, const bf16* __restrict__ wob, float* __restrict__ out) {
  __shared__ __align__(16) bf16 As[64 * 32];
  __shared__ __align__(16) bf16 Bs[128 * 32];
  const int t = threadIdx.x;
  const int lane = t & 63;
  const int wave = t >> 6;
  const int wm = (wave >> 1) * 32;
  const int wn = (wave & 1) * 64;
  const int m0 = blockIdx.x * 64;
  const int n0 = blockIdx.y * 128;
  const int r = t >> 2;
  const int ck = (t & 3) * 8;
  const int l15 = lane & 15;
  const int koff = (lane >> 4) * 8;

  f32x4 acc[2][4] = {};

  for (int k0 = 0; k0 < KD; k0 += 32) {
    gld16(ab + (size_t)(m0 + r) * KD + k0 + ck, As + t * 8);
    gld16(wob + (size_t)(n0 + r) * KD + k0 + ck, Bs + t * 8);
    gld16(wob + (size_t)(n0 + 64 + r) * KD + k0 + ck, Bs + 2048 + t * 8);
    __syncthreads();
    bf16x8 af[2], bfr[4];
#pragma unroll
    for (int mt = 0; mt < 2; ++mt)
      af[mt] = *(const bf16x8*)(As + (wm + mt * 16 + l15) * 32 + koff);
#pragma unroll
    for (int nt = 0; nt < 4; ++nt)
      bfr[nt] = *(const bf16x8*)(Bs + (wn + nt * 16 + l15) * 32 + koff);
#pragma unroll
    for (int mt = 0; mt < 2; ++mt)
#pragma unroll
      for (int nt = 0; nt < 4; ++nt)
        acc[mt][nt] = __builtin_amdgcn_mfma_f32_16x16x32_bf16(af[mt], bfr[nt], acc[mt][nt], 0, 0, 0);
    __syncthreads();
  }
  const int colb = n0 + wn + l15;
  const int rowb = m0 + wm + (lane >> 4) * 4;
#pragma unroll
  for (int mt = 0; mt < 2; ++mt)
#pragma unroll
    for (int nt = 0; nt < 4; ++nt)
#pragma unroll
      for (int rr = 0; rr < 4; ++rr)
        out[(size_t)(rowb + mt * 16 + rr) * ND + colb + nt * 16] = acc[mt][nt][rr];
}

// ---------------- attention ----------------
// grid (1280, 1), 256 threads.
//  bx < 1024 : sparse rows; wave handles one row i for ALL 16 heads (2KB wave-loads).
//  bx >= 1024: row-0 partials per (b, h, 256-col chunk).
__global__ __launch_bounds__(256) void attn_kernel(const bf16* __restrict__ q, const bf16* __restrict__ k,
                                                   const bf16* __restrict__ v, bf16* __restrict__ o,
                                                   const int* __restrict__ ctab,
                                                   float* __restrict__ pm, float* __restrict__ pz,
                                                   float* __restrict__ pv) {
  const int t = threadIdx.x;
  const int lane = t & 63;
  const int w = t >> 6;

  __shared__ float sbuf[256];
  __shared__ float redm[4], redz[4];
  __shared__ float part[4][64];

  if (blockIdx.x < 1024) {
    const int b = blockIdx.x >> 9;
    const int tt = blockIdx.x & 511;
    const int tile = ((tt & 7) << 6) + (tt >> 3);   // XCD swizzle
    const int i = tile * 4 + 1 + w;
    if (i >= SEQ_L) return;   // wave-uniform
    const size_t bb = (size_t)b * SEQ_L * DM;
    const int eo = lane * 16;

    const bf16* qrow = q + bb + (size_t)i * DM + eo;
    bf16x8 qv0 = *(const bf16x8*)(qrow);
    bf16x8 qv1 = *(const bf16x8*)(qrow + 8);

    const int4* cp = (const int4*)(ctab + i * 12);
    int4 ca = cp[0], cb = cp[1], cc = cp[2];
    int cols[11] = {ca.x, ca.y, ca.z, ca.w, cb.x, cb.y, cb.z, cb.w, cc.x, cc.y, cc.z};

    float sv[11];
#pragma unroll
    for (int c = 0; c < 11; ++c) {
      int cj = cols[c] < 0 ? 0 : cols[c];
      const bf16* krow = k + bb + (size_t)cj * DM + eo;
      bf16x8 kv0 = *(const bf16x8*)(krow);
      bf16x8 kv1 = *(const bf16x8*)(krow + 8);
      float acc = 0.f;
#pragma unroll
      for (int e = 0; e < 8; ++e)
        acc += (float)qv0[e] * (float)kv0[e] + (float)qv1[e] * (float)kv1[e];
      sv[c] = acc;
    }
#pragma unroll
    for (int c = 0; c < 11; ++c) {
      sv[c] += __shfl_xor(sv[c], 1);
      sv[c] += __shfl_xor(sv[c], 2);
      sv[c] = cols[c] < 0 ? -1e30f : sv[c] * 0.125f;
    }
    float m = -1e30f;
#pragma unroll
    for (int c = 0; c < 11; ++c) m = fmaxf(m, sv[c]);
    float z = 0.f;
#pragma unroll
    for (int c = 0; c < 11; ++c) { sv[c] = __expf(sv[c] - m); z += sv[c]; }
    const float inv = 1.f / z;

    float oa[16] = {};
#pragma unroll
    for (int c = 0; c < 11; ++c) {
      int cj = cols[c] < 0 ? 0 : cols[c];
      const bf16* vrow = v + bb + (size_t)cj * DM + eo;
      bf16x8 vv0 = *(const bf16x8*)(vrow);
      bf16x8 vv1 = *(const bf16x8*)(vrow + 8);
#pragma unroll
      for (int e = 0; e < 8; ++e) {
        oa[e]     += sv[c] * (float)vv0[e];
        oa[8 + e] += sv[c] * (float)vv1[e];
      }
    }
    bf16x8 ov0, ov1;
#pragma unroll
    for (int e = 0; e < 8; ++e) {
      ov0[e] = (bf16)(oa[e] * inv);
      ov1[e] = (bf16)(oa[8 + e] * inv);
    }
    bf16* orow = o + bb + (size_t)i * DM + eo;
    *(bf16x8*)(orow) = ov0;
    *(bf16x8*)(orow + 8) = ov1;
    return;
  }

  // ---- row-0 partial: (b, h, chunk of 256 cols) ----
  const int idx = blockIdx.x - 1024;    // 0..255
  const int b = idx >> 7;
  const int rem = idx & 127;
  const int h = rem >> 3;
  const int c = rem & 7;
  const size_t hb = (size_t)b * SEQ_L * DM + (size_t)h * HD;
  const int j = c * 256 + t;

  bf16x8 qv8[8];
#pragma unroll
  for (int cc = 0; cc < 8; ++cc) qv8[cc] = *(const bf16x8*)(q + hb + cc * 8);

  float acc = 0.f;
#pragma unroll
  for (int cc = 0; cc < 8; ++cc) {
    bf16x8 kv = *(const bf16x8*)(k + hb + (size_t)j * DM + cc * 8);
#pragma unroll
    for (int e = 0; e < 8; ++e) acc += (float)qv8[cc][e] * (float)kv[e];
  }
  float s = acc * 0.125f;
  float mloc = s;
#pragma unroll
  for (int off = 32; off > 0; off >>= 1) mloc = fmaxf(mloc, __shfl_xor(mloc, off));
  if (lane == 0) redm[w] = mloc;
  __syncthreads();
  const float m = fmaxf(fmaxf(redm[0], redm[1]), fmaxf(redm[2], redm[3]));

  float e = __expf(s - m);
  sbuf[t] = e;
  float zloc = e;
#pragma unroll
  for (int off = 32; off > 0; off >>= 1) zloc += __shfl_xor(zloc, off);
  if (lane == 0) redz[w] = zloc;
  __syncthreads();
  const float zc = redz[0] + redz[1] + redz[2] + redz[3];

  float oa = 0.f;
  for (int jj = w; jj < 256; jj += 4)
    oa += sbuf[jj] * (float)v[hb + (size_t)(c * 256 + jj) * DM + lane];
  part[w][lane] = oa;
  __syncthreads();
  if (t < 64) pv[idx * 64 + t] = part[0][t] + part[1][t] + part[2][t] + part[3][t];
  if (t == 0) { pm[idx] = m; pz[idx] = zc; }
}

// combine row-0 partials: one block per (b,h), 64 threads (lane = dim)
__global__ __launch_bounds__(64) void row0_combine_kernel(const float* __restrict__ pm,
                                                          const float* __restrict__ pz,
                                                          const float* __restrict__ pv,
                                                          bf16* __restrict__ o) {
  const int bh = blockIdx.x;
  const int b = bh >> 4, h = bh & 15;
  const int d = threadIdx.x;
  const int base = bh * 8;
  float M = -1e30f;
#pragma unroll
  for (int c = 0; c < 8; ++c) M = fmaxf(M, pm[base + c]);
  float Z = 0.f, od = 0.f;
#pragma unroll
  for (int c = 0; c < 8; ++c) {
    float sc = __expf(pm[base + c] - M);
    Z += pz[base + c] * sc;
    od += pv[(base + c) * 64 + d] * sc;
  }
  o[(size_t)b * SEQ_L * DM + (size_t)h * HD + d] = (bf16)(od / Z);
}

// ---------------- launch ----------------
extern "C" void kernel_launch(void* const* d_in, const int* in_sizes, int n_in,
                              void* d_out, int out_size, void* d_ws, size_t ws_size,
                              hipStream_t stream) {
  const float* x     = (const float*)d_in[0];
  const float* freqs = (const float*)d_in[1];
  const float* wq    = (const float*)d_in[2];
  const float* wk    = (const float*)d_in[3];
  const float* wv    = (const float*)d_in[4];
  const float* wo    = (const float*)d_in[5];
  float* out = (float*)d_out;

  char* ws = (char*)d_ws;
  bf16* xb  = (bf16*)(ws + 0);          // 8 MiB
  bf16* wqb = (bf16*)(ws + 8388608);    // 2 MiB each
  bf16* wkb = (bf16*)(ws + 10485760);
  bf16* wvb = (bf16*)(ws + 12582912);
  bf16* wob = (bf16*)(ws + 14680064);
  bf16* qb  = (bf16*)(ws + 16777216);   // 8 MiB [B,L,H,HD]
  bf16* kb  = (bf16*)(ws + 25165824);
  bf16* vb  = (bf16*)(ws + 33554432);
  bf16* ab  = (bf16*)(ws + 41943040);   // 8 MiB; end 48 MiB
  int*   ctab = (int*)(ws + 50331648);  // 96 KB (own region — prep runs before qkv now)
  float* pm   = (float*)(ws + 50462720);
  float* pz   = (float*)(ws + 50463744);
  float* pv   = (float*)(ws + 50464768);  // 64 KB
  (void)ws_size;

  prep_kernel<<<8200, 256, 0, stream>>>(x, wq, wk, wv, wo, xb, wqb, wkb, wvb, wob, ctab);
  qkv_gemm_kernel<<<dim3(32, 8, 3), 256, 0, stream>>>(xb, wqb, wkb, wvb, qb, kb, vb, freqs);
  attn_kernel<<<dim3(1280, 1), 256, 0, stream>>>(qb, kb, vb, ab, ctab, pm, pz, pv);
  row0_combine_kernel<<<32, 64, 0, stream>>>(pm, pz, pv, ab);
  out_gemm_kernel<<<dim3(64, 8), 256, 0, stream>>>(ab, wob, out);
}

// Round 8
// 173.755 us; speedup vs baseline: 9.4951x; 1.0120x over previous
//
#include <hip/hip_runtime.h>
#include <math.h>

#define SEQ_L 2048
#define DM 1024
#define NH 16
#define HD 64
#define NB 2
#define KD 1024   // GEMM K
#define ND 1024   // GEMM N

typedef __bf16 bf16;
typedef __bf16 bf16x8 __attribute__((ext_vector_type(8)));
typedef __bf16 bf16x4 __attribute__((ext_vector_type(4)));
typedef float f32x4 __attribute__((ext_vector_type(4)));

// ---------------- jax threefry2x32, key = (0, 42); partitionable random_bits ----------------
__device__ inline uint32_t rotl32(uint32_t v, int n) { return (v << n) | (v >> (32 - n)); }

__device__ inline void threefry(uint32_t x0, uint32_t x1, uint32_t* o0, uint32_t* o1) {
  const uint32_t ks0 = 0u, ks1 = 42u, ks2 = 0u ^ 42u ^ 0x1BD11BDAu;
  x0 += ks0; x1 += ks1;
#define TF_R(rr) { x0 += x1; x1 = rotl32(x1, rr); x1 ^= x0; }
  TF_R(13) TF_R(15) TF_R(26) TF_R(6)
  x0 += ks1; x1 += ks2 + 1u;
  TF_R(17) TF_R(29) TF_R(16) TF_R(24)
  x0 += ks2; x1 += ks0 + 2u;
  TF_R(13) TF_R(15) TF_R(26) TF_R(6)
  x0 += ks0; x1 += ks1 + 3u;
  TF_R(17) TF_R(29) TF_R(16) TF_R(24)
  x0 += ks1; x1 += ks2 + 4u;
  TF_R(13) TF_R(15) TF_R(26) TF_R(6)
  x0 += ks2; x1 += ks0 + 5u;
#undef TF_R
  *o0 = x0; *o1 = x1;
}

// jax_threefry_partitionable=True: counter (hi=0, lo=flat_idx), bits = o0 ^ o1.
__device__ inline int rand_col(int i, int s) {
  uint32_t o0, o1;
  threefry(0u, (uint32_t)(2 * i + s), &o0, &o1);
  uint32_t bits = o0 ^ o1;
  float u = __uint_as_float((bits >> 9) | 0x3f800000u) - 1.0f;
  return (int)floorf(u * (float)(i + 1));
}

// ---------------- prep: conversions + ctab + rope cos/sin table ----------------
// grid (8456, 1), 256 thr:
//   bx <  4096 : x  (4M elems, float4->bf16x4)
//   4096..8191 : weights (4 x 1M elems)
//   8192..8199 : ctab rows
//   8200..8455 : rope table (2048 x 32 float2)
__global__ void prep_kernel(const float* __restrict__ x,
                            const float* __restrict__ w0, const float* __restrict__ w1,
                            const float* __restrict__ w2, const float* __restrict__ w3,
                            const float* __restrict__ freqs,
                            bf16* __restrict__ xb,
                            bf16* __restrict__ o0, bf16* __restrict__ o1,
                            bf16* __restrict__ o2, bf16* __restrict__ o3,
                            int* __restrict__ ctab, float2* __restrict__ rtab) {
  const int bx = blockIdx.x;
  const int t = threadIdx.x;
  if (bx < 8192) {
    const float* src;
    bf16* dst;
    int idx;
    if (bx < 4096) { src = x; dst = xb; idx = bx * 256 + t; }
    else {
      int widx = bx - 4096;
      int wsel = widx >> 10;
      switch (wsel) {
        case 0: src = w0; dst = o0; break;
        case 1: src = w1; dst = o1; break;
        case 2: src = w2; dst = o2; break;
        default: src = w3; dst = o3; break;
      }
      idx = (widx & 1023) * 256 + t;
    }
    float4 vv = ((const float4*)src)[idx];
    bf16x4 ov;
    ov[0] = (bf16)vv.x; ov[1] = (bf16)vv.y; ov[2] = (bf16)vv.z; ov[3] = (bf16)vv.w;
    *(bf16x4*)(dst + (size_t)idx * 4) = ov;
    return;
  }
  if (bx < 8200) {
    // column table
    const int i = (bx - 8192) * 256 + t;    // 0..2047
    int cols[11]; int nc = 0;
    if (i >= 1) {
      int lo = i - 7; if (lo < 0) lo = 0;
      for (int j = lo; j <= i; ++j) cols[nc++] = j;
      if (lo > 0) cols[nc++] = 0;
#pragma unroll
      for (int s = 0; s < 2; ++s) {
        int rj = rand_col(i, s);
        bool dup = false;
        for (int c2 = 0; c2 < nc; ++c2) dup |= (cols[c2] == rj);
        if (!dup) cols[nc++] = rj;
      }
    }
    for (int c2 = nc; c2 < 11; ++c2) cols[c2] = -1;
#pragma unroll
    for (int c2 = 0; c2 < 11; ++c2) ctab[i * 12 + c2] = cols[c2];
    ctab[i * 12 + 11] = nc;
    return;
  }
  // rope table: idx -> (l, jj)
  const int idx = (bx - 8200) * 256 + t;    // 0..65535
  float s, c;
  sincosf(freqs[idx], &s, &c);              // freqs flat = l*32+jj
  rtab[idx] = make_float2(c, s);
}

// ---------------- GEMM: C[m][n] = sum_k A[m][k] * W[n][k]  (B^T layout, m97 pattern) --------
__device__ inline void gld16(const bf16* g, bf16* l) {
  __builtin_amdgcn_global_load_lds((const __attribute__((address_space(1))) void*)g,
                                   (__attribute__((address_space(3))) void*)l, 16, 0, 0);
}

// 128x128 tile; optional fused RoPE epilogue via precomputed cos/sin table.
template <typename OutT>
__device__ inline void gemm_bt_body(const bf16* __restrict__ A, const bf16* __restrict__ W,
                                    OutT* __restrict__ C, const float2* __restrict__ rtab) {
  __shared__ __align__(16) bf16 As[128 * 32];
  __shared__ __align__(16) bf16 Bs[128 * 32];
  const int t = threadIdx.x;
  const int lane = t & 63;
  const int wave = t >> 6;
  const int wm = (wave >> 1) * 64;
  const int wn = (wave & 1) * 64;
  const int m0 = blockIdx.x * 128;
  const int n0 = blockIdx.y * 128;
  const int r = t >> 2;
  const int ck = (t & 3) * 8;
  const int l15 = lane & 15;
  const int koff = (lane >> 4) * 8;

  f32x4 acc[4][4] = {};

  for (int k0 = 0; k0 < KD; k0 += 32) {
    gld16(A + (size_t)(m0 + r) * KD + k0 + ck, As + t * 8);
    gld16(A + (size_t)(m0 + 64 + r) * KD + k0 + ck, As + 2048 + t * 8);
    gld16(W + (size_t)(n0 + r) * KD + k0 + ck, Bs + t * 8);
    gld16(W + (size_t)(n0 + 64 + r) * KD + k0 + ck, Bs + 2048 + t * 8);
    __syncthreads();
    bf16x8 af[4], bfr[4];
#pragma unroll
    for (int mt = 0; mt < 4; ++mt)
      af[mt] = *(const bf16x8*)(As + (wm + mt * 16 + l15) * 32 + koff);
#pragma unroll
    for (int nt = 0; nt < 4; ++nt)
      bfr[nt] = *(const bf16x8*)(Bs + (wn + nt * 16 + l15) * 32 + koff);
#pragma unroll
    for (int mt = 0; mt < 4; ++mt)
#pragma unroll
      for (int nt = 0; nt < 4; ++nt)
        acc[mt][nt] = __builtin_amdgcn_mfma_f32_16x16x32_bf16(af[mt], bfr[nt], acc[mt][nt], 0, 0, 0);
    __syncthreads();
  }
  // C/D layout: col = lane&15, row = (lane>>4)*4 + reg   [verified m89]
  const int colb = n0 + wn + l15;
  const int rowb = m0 + wm + (lane >> 4) * 4;
  const int odd = l15 & 1;
#pragma unroll
  for (int mt = 0; mt < 4; ++mt)
#pragma unroll
    for (int nt = 0; nt < 4; ++nt) {
      const int col = colb + nt * 16;
      const int jj = (col & 63) >> 1;
#pragma unroll
      for (int rr = 0; rr < 4; ++rr) {
        float val = acc[mt][nt][rr];
        if (rtab) {
          const int row = rowb + mt * 16 + rr;
          const int l = row & (SEQ_L - 1);
          float2 cs = rtab[l * 32 + jj];
          float partner = __shfl_xor(val, 1);
          val = odd ? val * cs.x + partner * cs.y : val * cs.x - partner * cs.y;
        }
        C[(size_t)(rowb + mt * 16 + rr) * ND + colb + nt * 16] = (OutT)val;
      }
    }
}

// grid (32,8,3) = 768 blocks; 3 blocks/CU -> exactly one residency pass (no tail)
__global__ __launch_bounds__(256, 3) void qkv_gemm_kernel(
    const bf16* __restrict__ xb, const bf16* __restrict__ wqb, const bf16* __restrict__ wkb,
    const bf16* __restrict__ wvb, bf16* __restrict__ qb, bf16* __restrict__ kb, bf16* __restrict__ vb,
    const float2* __restrict__ rtab) {
  const bf16* W = blockIdx.z == 0 ? wqb : blockIdx.z == 1 ? wkb : wvb;
  bf16* O = blockIdx.z == 0 ? qb : blockIdx.z == 1 ? kb : vb;
  const float2* rt = blockIdx.z < 2 ? rtab : nullptr;   // rope on q,k only
  gemm_bt_body<bf16>(xb, W, O, rt);
}

// ---- out-projection GEMM: 64x128 tile, grid (64,8) = 512 blocks = 2 blocks/CU ----
// Blocks touching rows 0 (x==0) / 2048 (x==32) first materialize the row-0 attention
// output from the (pm,pz,pv) partials (redundant identical writes across n-blocks: benign).
__global__ __launch_bounds__(256, 2) void out_gemm_kernel(
    bf16* __restrict__ ab, const bf16* __restrict__ wob, float* __restrict__ out,
    const float* __restrict__ pm, const float* __restrict__ pz, const float* __restrict__ pv) {
  const int t = threadIdx.x;
  const int m0 = blockIdx.x * 64;
  const int n0 = blockIdx.y * 128;

  if (blockIdx.x == 0 || blockIdx.x == 32) {
    const int b = blockIdx.x == 0 ? 0 : 1;
#pragma unroll
    for (int e = t; e < DM; e += 256) {
      const int h = e >> 6, d = e & 63;
      const int base = b * 128 + h * 8;
      float M = -1e30f;
#pragma unroll
      for (int c = 0; c < 8; ++c) M = fmaxf(M, pm[base + c]);
      float Z = 0.f, od = 0.f;
#pragma unroll
      for (int c = 0; c < 8; ++c) {
        float sc = __expf(pm[base + c] - M);
        Z += pz[base + c] * sc;
        od += pv[(base + c) * 64 + d] * sc;
      }
      ab[(size_t)b * SEQ_L * DM + e] = (bf16)(od / Z);
    }
    __syncthreads();   // drain stores before staging reads the same row
  }

  __shared__ __align__(16) bf16 As[64 * 32];
  __shared__ __align__(16) bf16 Bs[128 * 32];
  const int lane = t & 63;
  const int wave = t >> 6;
  const int wm = (wave >> 1) * 32;
  const int wn = (wave & 1) * 64;
  const int r = t >> 2;
  const int ck = (t & 3) * 8;
  const int l15 = lane & 15;
  const int koff = (lane >> 4) * 8;

  f32x4 acc[2][4] = {};

  for (int k0 = 0; k0 < KD; k0 += 32) {
    gld16(ab + (size_t)(m0 + r) * KD + k0 + ck, As + t * 8);
    gld16(wob + (size_t)(n0 + r) * KD + k0 + ck, Bs + t * 8);
    gld16(wob + (size_t)(n0 + 64 + r) * KD + k0 + ck, Bs + 2048 + t * 8);
    __syncthreads();
    bf16x8 af[2], bfr[4];
#pragma unroll
    for (int mt = 0; mt < 2; ++mt)
      af[mt] = *(const bf16x8*)(As + (wm + mt * 16 + l15) * 32 + koff);
#pragma unroll
    for (int nt = 0; nt < 4; ++nt)
      bfr[nt] = *(const bf16x8*)(Bs + (wn + nt * 16 + l15) * 32 + koff);
#pragma unroll
    for (int mt = 0; mt < 2; ++mt)
#pragma unroll
      for (int nt = 0; nt < 4; ++nt)
        acc[mt][nt] = __builtin_amdgcn_mfma_f32_16x16x32_bf16(af[mt], bfr[nt], acc[mt][nt], 0, 0, 0);
    __syncthreads();
  }
  const int colb = n0 + wn + l15;
  const int rowb = m0 + wm + (lane >> 4) * 4;
#pragma unroll
  for (int mt = 0; mt < 2; ++mt)
#pragma unroll
    for (int nt = 0; nt < 4; ++nt)
#pragma unroll
      for (int rr = 0; rr < 4; ++rr)
        out[(size_t)(rowb + mt * 16 + rr) * ND + colb + nt * 16] = acc[mt][nt][rr];
}

// ---------------- attention ----------------
// grid (1280, 1), 256 threads.
//  bx < 1024 : sparse rows; wave handles one row i for ALL 16 heads (2KB wave-loads).
//  bx >= 1024: row-0 partials per (b, h, 256-col chunk) -> pm/pz/pv (combined in out_gemm).
__global__ __launch_bounds__(256) void attn_kernel(const bf16* __restrict__ q, const bf16* __restrict__ k,
                                                   const bf16* __restrict__ v, bf16* __restrict__ o,
                                                   const int* __restrict__ ctab,
                                                   float* __restrict__ pm, float* __restrict__ pz,
                                                   float* __restrict__ pv) {
  const int t = threadIdx.x;
  const int lane = t & 63;
  const int w = t >> 6;

  __shared__ float sbuf[256];
  __shared__ float redm[4], redz[4];
  __shared__ float part[4][64];

  if (blockIdx.x < 1024) {
    const int b = blockIdx.x >> 9;
    const int tt = blockIdx.x & 511;
    const int tile = ((tt & 7) << 6) + (tt >> 3);   // XCD swizzle
    const int i = tile * 4 + 1 + w;
    if (i >= SEQ_L) return;   // wave-uniform
    const size_t bb = (size_t)b * SEQ_L * DM;
    const int eo = lane * 16;

    const bf16* qrow = q + bb + (size_t)i * DM + eo;
    bf16x8 qv0 = *(const bf16x8*)(qrow);
    bf16x8 qv1 = *(const bf16x8*)(qrow + 8);

    const int4* cp = (const int4*)(ctab + i * 12);
    int4 ca = cp[0], cb = cp[1], cc = cp[2];
    int cols[11] = {ca.x, ca.y, ca.z, ca.w, cb.x, cb.y, cb.z, cb.w, cc.x, cc.y, cc.z};

    float sv[11];
#pragma unroll
    for (int c = 0; c < 11; ++c) {
      int cj = cols[c] < 0 ? 0 : cols[c];
      const bf16* krow = k + bb + (size_t)cj * DM + eo;
      bf16x8 kv0 = *(const bf16x8*)(krow);
      bf16x8 kv1 = *(const bf16x8*)(krow + 8);
      float acc = 0.f;
#pragma unroll
      for (int e = 0; e < 8; ++e)
        acc += (float)qv0[e] * (float)kv0[e] + (float)qv1[e] * (float)kv1[e];
      sv[c] = acc;
    }
#pragma unroll
    for (int c = 0; c < 11; ++c) {
      sv[c] += __shfl_xor(sv[c], 1);
      sv[c] += __shfl_xor(sv[c], 2);
      sv[c] = cols[c] < 0 ? -1e30f : sv[c] * 0.125f;
    }
    float m = -1e30f;
#pragma unroll
    for (int c = 0; c < 11; ++c) m = fmaxf(m, sv[c]);
    float z = 0.f;
#pragma unroll
    for (int c = 0; c < 11; ++c) { sv[c] = __expf(sv[c] - m); z += sv[c]; }
    const float inv = 1.f / z;

    float oa[16] = {};
#pragma unroll
    for (int c = 0; c < 11; ++c) {
      int cj = cols[c] < 0 ? 0 : cols[c];
      const bf16* vrow = v + bb + (size_t)cj * DM + eo;
      bf16x8 vv0 = *(const bf16x8*)(vrow);
      bf16x8 vv1 = *(const bf16x8*)(vrow + 8);
#pragma unroll
      for (int e = 0; e < 8; ++e) {
        oa[e]     += sv[c] * (float)vv0[e];
        oa[8 + e] += sv[c] * (float)vv1[e];
      }
    }
    bf16x8 ov0, ov1;
#pragma unroll
    for (int e = 0; e < 8; ++e) {
      ov0[e] = (bf16)(oa[e] * inv);
      ov1[e] = (bf16)(oa[8 + e] * inv);
    }
    bf16* orow = o + bb + (size_t)i * DM + eo;
    *(bf16x8*)(orow) = ov0;
    *(bf16x8*)(orow + 8) = ov1;
    return;
  }

  // ---- row-0 partial: (b, h, chunk of 256 cols) ----
  const int idx = blockIdx.x - 1024;    // 0..255
  const int b = idx >> 7;
  const int rem = idx & 127;
  const int h = rem >> 3;
  const int c = rem & 7;
  const size_t hb = (size_t)b * SEQ_L * DM + (size_t)h * HD;
  const int j = c * 256 + t;

  bf16x8 qv8[8];
#pragma unroll
  for (int cc = 0; cc < 8; ++cc) qv8[cc] = *(const bf16x8*)(q + hb + cc * 8);

  float acc = 0.f;
#pragma unroll
  for (int cc = 0; cc < 8; ++cc) {
    bf16x8 kv = *(const bf16x8*)(k + hb + (size_t)j * DM + cc * 8);
#pragma unroll
    for (int e = 0; e < 8; ++e) acc += (float)qv8[cc][e] * (float)kv[e];
  }
  float s = acc * 0.125f;
  float mloc = s;
#pragma unroll
  for (int off = 32; off > 0; off >>= 1) mloc = fmaxf(mloc, __shfl_xor(mloc, off));
  if (lane == 0) redm[w] = mloc;
  __syncthreads();
  const float m = fmaxf(fmaxf(redm[0], redm[1]), fmaxf(redm[2], redm[3]));

  float e = __expf(s - m);
  sbuf[t] = e;
  float zloc = e;
#pragma unroll
  for (int off = 32; off > 0; off >>= 1) zloc += __shfl_xor(zloc, off);
  if (lane == 0) redz[w] = zloc;
  __syncthreads();
  const float zc = redz[0] + redz[1] + redz[2] + redz[3];

  float oa = 0.f;
  for (int jj = w; jj < 256; jj += 4)
    oa += sbuf[jj] * (float)v[hb + (size_t)(c * 256 + jj) * DM + lane];
  part[w][lane] = oa;
  __syncthreads();
  if (t < 64) pv[idx * 64 + t] = part[0][t] + part[1][t] + part[2][t] + part[3][t];
  if (t == 0) { pm[idx] = m; pz[idx] = zc; }
}

// ---------------- launch ----------------
extern "C" void kernel_launch(void* const* d_in, const int* in_sizes, int n_in,
                              void* d_out, int out_size, void* d_ws, size_t ws_size,
                              hipStream_t stream) {
  const float* x     = (const float*)d_in[0];
  const float* freqs = (const float*)d_in[1];
  const float* wq    = (const float*)d_in[2];
  const float* wk    = (const float*)d_in[3];
  const float* wv    = (const float*)d_in[4];
  const float* wo    = (const float*)d_in[5];
  float* out = (float*)d_out;

  char* ws = (char*)d_ws;
  bf16* xb  = (bf16*)(ws + 0);          // 8 MiB
  bf16* wqb = (bf16*)(ws + 8388608);    // 2 MiB each
  bf16* wkb = (bf16*)(ws + 10485760);
  bf16* wvb = (bf16*)(ws + 12582912);
  bf16* wob = (bf16*)(ws + 14680064);
  bf16* qb  = (bf16*)(ws + 16777216);   // 8 MiB [B,L,H,HD]
  bf16* kb  = (bf16*)(ws + 25165824);
  bf16* vb  = (bf16*)(ws + 33554432);
  bf16* ab  = (bf16*)(ws + 41943040);   // 8 MiB; end 48 MiB
  int*    ctab = (int*)(ws + 50331648); // 96 KB
  float*  pm   = (float*)(ws + 50462720);
  float*  pz   = (float*)(ws + 50463744);
  float*  pv   = (float*)(ws + 50464768);   // 64 KB
  float2* rtab = (float2*)(ws + 50593792);  // 512 KB rope cos/sin table
  (void)ws_size;

  prep_kernel<<<8456, 256, 0, stream>>>(x, wq, wk, wv, wo, freqs, xb, wqb, wkb, wvb, wob, ctab, rtab);
  qkv_gemm_kernel<<<dim3(32, 8, 3), 256, 0, stream>>>(xb, wqb, wkb, wvb, qb, kb, vb, rtab);
  attn_kernel<<<dim3(1280, 1), 256, 0, stream>>>(qb, kb, vb, ab, ctab, pm, pz, pv);
  out_gemm_kernel<<<dim3(64, 8), 256, 0, stream>>>(ab, wob, out, pm, pz, pv);
}

// Round 9
// 170.905 us; speedup vs baseline: 9.6535x; 1.0167x over previous
//
#include <hip/hip_runtime.h>
#include <math.h>

#define SEQ_L 2048
#define DM 1024
#define NH 16
#define HD 64
#define NB 2
#define KD 1024   // GEMM K
#define ND 1024   // GEMM N

typedef __bf16 bf16;
typedef __bf16 bf16x8 __attribute__((ext_vector_type(8)));
typedef __bf16 bf16x4 __attribute__((ext_vector_type(4)));
typedef __bf16 bf16x2 __attribute__((ext_vector_type(2)));
typedef float f32x4 __attribute__((ext_vector_type(4)));

// ---------------- jax threefry2x32, key = (0, 42); partitionable random_bits ----------------
__device__ inline uint32_t rotl32(uint32_t v, int n) { return (v << n) | (v >> (32 - n)); }

__device__ inline void threefry(uint32_t x0, uint32_t x1, uint32_t* o0, uint32_t* o1) {
  const uint32_t ks0 = 0u, ks1 = 42u, ks2 = 0u ^ 42u ^ 0x1BD11BDAu;
  x0 += ks0; x1 += ks1;
#define TF_R(rr) { x0 += x1; x1 = rotl32(x1, rr); x1 ^= x0; }
  TF_R(13) TF_R(15) TF_R(26) TF_R(6)
  x0 += ks1; x1 += ks2 + 1u;
  TF_R(17) TF_R(29) TF_R(16) TF_R(24)
  x0 += ks2; x1 += ks0 + 2u;
  TF_R(13) TF_R(15) TF_R(26) TF_R(6)
  x0 += ks0; x1 += ks1 + 3u;
  TF_R(17) TF_R(29) TF_R(16) TF_R(24)
  x0 += ks1; x1 += ks2 + 4u;
  TF_R(13) TF_R(15) TF_R(26) TF_R(6)
  x0 += ks2; x1 += ks0 + 5u;
#undef TF_R
  *o0 = x0; *o1 = x1;
}

// jax_threefry_partitionable=True: counter (hi=0, lo=flat_idx), bits = o0 ^ o1.
__device__ inline int rand_col(int i, int s) {
  uint32_t o0, o1;
  threefry(0u, (uint32_t)(2 * i + s), &o0, &o1);
  uint32_t bits = o0 ^ o1;
  float u = __uint_as_float((bits >> 9) | 0x3f800000u) - 1.0f;
  return (int)floorf(u * (float)(i + 1));
}

// ---------------- prep: conversions + ctab + rope cos/sin table ----------------
__global__ void prep_kernel(const float* __restrict__ x,
                            const float* __restrict__ w0, const float* __restrict__ w1,
                            const float* __restrict__ w2, const float* __restrict__ w3,
                            const float* __restrict__ freqs,
                            bf16* __restrict__ xb,
                            bf16* __restrict__ o0, bf16* __restrict__ o1,
                            bf16* __restrict__ o2, bf16* __restrict__ o3,
                            int* __restrict__ ctab, float2* __restrict__ rtab) {
  const int bx = blockIdx.x;
  const int t = threadIdx.x;
  if (bx < 8192) {
    const float* src;
    bf16* dst;
    int idx;
    if (bx < 4096) { src = x; dst = xb; idx = bx * 256 + t; }
    else {
      int widx = bx - 4096;
      int wsel = widx >> 10;
      switch (wsel) {
        case 0: src = w0; dst = o0; break;
        case 1: src = w1; dst = o1; break;
        case 2: src = w2; dst = o2; break;
        default: src = w3; dst = o3; break;
      }
      idx = (widx & 1023) * 256 + t;
    }
    float4 vv = ((const float4*)src)[idx];
    bf16x4 ov;
    ov[0] = (bf16)vv.x; ov[1] = (bf16)vv.y; ov[2] = (bf16)vv.z; ov[3] = (bf16)vv.w;
    *(bf16x4*)(dst + (size_t)idx * 4) = ov;
    return;
  }
  if (bx < 8200) {
    const int i = (bx - 8192) * 256 + t;    // 0..2047
    int cols[11]; int nc = 0;
    if (i >= 1) {
      int lo = i - 7; if (lo < 0) lo = 0;
      for (int j = lo; j <= i; ++j) cols[nc++] = j;
      if (lo > 0) cols[nc++] = 0;
#pragma unroll
      for (int s = 0; s < 2; ++s) {
        int rj = rand_col(i, s);
        bool dup = false;
        for (int c2 = 0; c2 < nc; ++c2) dup |= (cols[c2] == rj);
        if (!dup) cols[nc++] = rj;
      }
    }
    for (int c2 = nc; c2 < 11; ++c2) cols[c2] = -1;
#pragma unroll
    for (int c2 = 0; c2 < 11; ++c2) ctab[i * 12 + c2] = cols[c2];
    ctab[i * 12 + 11] = nc;
    return;
  }
  const int idx = (bx - 8200) * 256 + t;    // 0..65535
  float s, c;
  sincosf(freqs[idx], &s, &c);
  rtab[idx] = make_float2(c, s);
}

// ---------------- GEMM common ----------------
__device__ inline void gld16(const bf16* g, bf16* l) {
  __builtin_amdgcn_global_load_lds((const __attribute__((address_space(1))) void*)g,
                                   (__attribute__((address_space(3))) void*)l, 16, 0, 0);
}

// 128x128 tile, BK=64, XOR-swizzled LDS (conflict-free frag reads), pair-packed
// bf16 epilogue with optional fused RoPE.
__device__ inline void gemm_bt_body(const bf16* __restrict__ A, const bf16* __restrict__ W,
                                    bf16* __restrict__ C, const float2* __restrict__ rtab) {
  __shared__ __align__(16) bf16 As[128 * 64];   // 16 KB
  __shared__ __align__(16) bf16 Bs[128 * 64];   // 16 KB
  const int t = threadIdx.x;
  const int lane = t & 63;
  const int wave = t >> 6;
  const int wm = (wave >> 1) * 64;
  const int wn = (wave & 1) * 64;
  const int m0 = blockIdx.x * 128;
  const int n0 = blockIdx.y * 128;
  const int l15 = lane & 15;
  const int kq = lane >> 4;          // 0..3

  f32x4 acc[4][4] = {};

  for (int k0 = 0; k0 < KD; k0 += 64) {
#pragma unroll
    for (int n = 0; n < 4; ++n) {
      const int s = n * 256 + t;               // 16B slot; lane-contiguous per wave
      const int row = s >> 3;                  // 0..127
      const int ch = (s & 7) ^ (row & 7);      // XOR bank swizzle
      gld16(A + (size_t)(m0 + row) * KD + k0 + ch * 8, As + s * 8);
      gld16(W + (size_t)(n0 + row) * KD + k0 + ch * 8, Bs + s * 8);
    }
    __syncthreads();
#pragma unroll
    for (int ks = 0; ks < 2; ++ks) {
      const int cb = ks * 4 + kq;              // k-chunk 0..7
      bf16x8 af[4], bfr[4];
#pragma unroll
      for (int mt = 0; mt < 4; ++mt) {
        const int row = wm + mt * 16 + l15;
        af[mt] = *(const bf16x8*)(As + row * 64 + ((cb ^ (row & 7)) * 8));
      }
#pragma unroll
      for (int nt = 0; nt < 4; ++nt) {
        const int row = wn + nt * 16 + l15;
        bfr[nt] = *(const bf16x8*)(Bs + row * 64 + ((cb ^ (row & 7)) * 8));
      }
#pragma unroll
      for (int mt = 0; mt < 4; ++mt)
#pragma unroll
        for (int nt = 0; nt < 4; ++nt)
          acc[mt][nt] = __builtin_amdgcn_mfma_f32_16x16x32_bf16(af[mt], bfr[nt], acc[mt][nt], 0, 0, 0);
    }
    __syncthreads();
  }
  // C/D layout: col = lane&15, row = (lane>>4)*4 + reg   [verified m89]
  const int colb = n0 + wn + l15;
  const int rowb = m0 + wm + (lane >> 4) * 4;
  const int odd = l15 & 1;
#pragma unroll
  for (int mt = 0; mt < 4; ++mt)
#pragma unroll
    for (int nt = 0; nt < 4; ++nt) {
      const int col = colb + nt * 16;
      const int jj = (col & 63) >> 1;
#pragma unroll
      for (int rr = 0; rr < 4; ++rr) {
        float val = acc[mt][nt][rr];
        float other = __shfl_xor(val, 1);      // partner column value
        if (!odd) {
          const int row = rowb + mt * 16 + rr;
          float lo, hi;
          if (rtab) {
            float2 cs = rtab[(row & (SEQ_L - 1)) * 32 + jj];
            lo = val * cs.x - other * cs.y;    // out_re
            hi = val * cs.y + other * cs.x;    // out_im
          } else { lo = val; hi = other; }
          bf16x2 p; p[0] = (bf16)lo; p[1] = (bf16)hi;
          *(bf16x2*)(C + (size_t)row * ND + col) = p;
        }
      }
    }
}

// grid (32,8,3) = 768 blocks; 3 blocks/CU
__global__ __launch_bounds__(256, 3) void qkv_gemm_kernel(
    const bf16* __restrict__ xb, const bf16* __restrict__ wqb, const bf16* __restrict__ wkb,
    const bf16* __restrict__ wvb, bf16* __restrict__ qb, bf16* __restrict__ kb, bf16* __restrict__ vb,
    const float2* __restrict__ rtab) {
  const bf16* W = blockIdx.z == 0 ? wqb : blockIdx.z == 1 ? wkb : wvb;
  bf16* O = blockIdx.z == 0 ? qb : blockIdx.z == 1 ? kb : vb;
  const float2* rt = blockIdx.z < 2 ? rtab : nullptr;   // rope on q,k only
  gemm_bt_body(xb, W, O, rt);
}

// ---- out-projection GEMM: 64x128 tile, BK=64, swizzled; grid (64,8) = 512 blocks ----
// Blocks x==0 / x==32 first materialize row-0 attention output from (pm,pz,pv).
__global__ __launch_bounds__(256, 2) void out_gemm_kernel(
    bf16* __restrict__ ab, const bf16* __restrict__ wob, float* __restrict__ out,
    const float* __restrict__ pm, const float* __restrict__ pz, const float* __restrict__ pv) {
  const int t = threadIdx.x;
  const int m0 = blockIdx.x * 64;
  const int n0 = blockIdx.y * 128;

  if (blockIdx.x == 0 || blockIdx.x == 32) {
    const int b = blockIdx.x == 0 ? 0 : 1;
#pragma unroll
    for (int e = t; e < DM; e += 256) {
      const int h = e >> 6, d = e & 63;
      const int base = b * 128 + h * 8;
      float M = -1e30f;
#pragma unroll
      for (int c = 0; c < 8; ++c) M = fmaxf(M, pm[base + c]);
      float Z = 0.f, od = 0.f;
#pragma unroll
      for (int c = 0; c < 8; ++c) {
        float sc = __expf(pm[base + c] - M);
        Z += pz[base + c] * sc;
        od += pv[(base + c) * 64 + d] * sc;
      }
      ab[(size_t)b * SEQ_L * DM + e] = (bf16)(od / Z);
    }
    __syncthreads();   // drain stores before staging reads the same row
  }

  __shared__ __align__(16) bf16 As[64 * 64];    // 8 KB
  __shared__ __align__(16) bf16 Bs[128 * 64];   // 16 KB
  const int lane = t & 63;
  const int wave = t >> 6;
  const int wm = (wave >> 1) * 32;
  const int wn = (wave & 1) * 64;
  const int l15 = lane & 15;
  const int kq = lane >> 4;

  f32x4 acc[2][4] = {};

  for (int k0 = 0; k0 < KD; k0 += 64) {
#pragma unroll
    for (int n = 0; n < 2; ++n) {
      const int s = n * 256 + t;               // 512 slots for As
      const int row = s >> 3;                  // 0..63
      const int ch = (s & 7) ^ (row & 7);
      gld16(ab + (size_t)(m0 + row) * KD + k0 + ch * 8, As + s * 8);
    }
#pragma unroll
    for (int n = 0; n < 4; ++n) {
      const int s = n * 256 + t;               // 1024 slots for Bs
      const int row = s >> 3;                  // 0..127
      const int ch = (s & 7) ^ (row & 7);
      gld16(wob + (size_t)(n0 + row) * KD + k0 + ch * 8, Bs + s * 8);
    }
    __syncthreads();
#pragma unroll
    for (int ks = 0; ks < 2; ++ks) {
      const int cb = ks * 4 + kq;
      bf16x8 af[2], bfr[4];
#pragma unroll
      for (int mt = 0; mt < 2; ++mt) {
        const int row = wm + mt * 16 + l15;
        af[mt] = *(const bf16x8*)(As + row * 64 + ((cb ^ (row & 7)) * 8));
      }
#pragma unroll
      for (int nt = 0; nt < 4; ++nt) {
        const int row = wn + nt * 16 + l15;
        bfr[nt] = *(const bf16x8*)(Bs + row * 64 + ((cb ^ (row & 7)) * 8));
      }
#pragma unroll
      for (int mt = 0; mt < 2; ++mt)
#pragma unroll
        for (int nt = 0; nt < 4; ++nt)
          acc[mt][nt] = __builtin_amdgcn_mfma_f32_16x16x32_bf16(af[mt], bfr[nt], acc[mt][nt], 0, 0, 0);
    }
    __syncthreads();
  }
  const int colb = n0 + wn + l15;
  const int rowb = m0 + wm + (lane >> 4) * 4;
#pragma unroll
  for (int mt = 0; mt < 2; ++mt)
#pragma unroll
    for (int nt = 0; nt < 4; ++nt)
#pragma unroll
      for (int rr = 0; rr < 4; ++rr)
        out[(size_t)(rowb + mt * 16 + rr) * ND + colb + nt * 16] = acc[mt][nt][rr];
}

// ---------------- attention ----------------
// grid (1280, 1), 256 threads.
//  bx < 1024 : sparse rows; wave handles one row i for ALL 16 heads (2KB wave-loads).
//  bx >= 1024: row-0 partials per (b, h, 256-col chunk) -> pm/pz/pv (combined in out_gemm).
__global__ __launch_bounds__(256) void attn_kernel(const bf16* __restrict__ q, const bf16* __restrict__ k,
                                                   const bf16* __restrict__ v, bf16* __restrict__ o,
                                                   const int* __restrict__ ctab,
                                                   float* __restrict__ pm, float* __restrict__ pz,
                                                   float* __restrict__ pv) {
  const int t = threadIdx.x;
  const int lane = t & 63;
  const int w = t >> 6;

  __shared__ float sbuf[256];
  __shared__ float redm[4], redz[4];
  __shared__ float part[4][64];

  if (blockIdx.x < 1024) {
    const int b = blockIdx.x >> 9;
    const int tt = blockIdx.x & 511;
    const int tile = ((tt & 7) << 6) + (tt >> 3);   // XCD swizzle
    const int i = tile * 4 + 1 + w;
    if (i >= SEQ_L) return;   // wave-uniform
    const size_t bb = (size_t)b * SEQ_L * DM;
    const int eo = lane * 16;

    const bf16* qrow = q + bb + (size_t)i * DM + eo;
    bf16x8 qv0 = *(const bf16x8*)(qrow);
    bf16x8 qv1 = *(const bf16x8*)(qrow + 8);

    const int4* cp = (const int4*)(ctab + i * 12);
    int4 ca = cp[0], cb = cp[1], cc = cp[2];
    int cols[11] = {ca.x, ca.y, ca.z, ca.w, cb.x, cb.y, cb.z, cb.w, cc.x, cc.y, cc.z};

    float sv[11];
#pragma unroll
    for (int c = 0; c < 11; ++c) {
      int cj = cols[c] < 0 ? 0 : cols[c];
      const bf16* krow = k + bb + (size_t)cj * DM + eo;
      bf16x8 kv0 = *(const bf16x8*)(krow);
      bf16x8 kv1 = *(const bf16x8*)(krow + 8);
      float acc = 0.f;
#pragma unroll
      for (int e = 0; e < 8; ++e)
        acc += (float)qv0[e] * (float)kv0[e] + (float)qv1[e] * (float)kv1[e];
      sv[c] = acc;
    }
#pragma unroll
    for (int c = 0; c < 11; ++c) {
      sv[c] += __shfl_xor(sv[c], 1);
      sv[c] += __shfl_xor(sv[c], 2);
      sv[c] = cols[c] < 0 ? -1e30f : sv[c] * 0.125f;
    }
    float m = -1e30f;
#pragma unroll
    for (int c = 0; c < 11; ++c) m = fmaxf(m, sv[c]);
    float z = 0.f;
#pragma unroll
    for (int c = 0; c < 11; ++c) { sv[c] = __expf(sv[c] - m); z += sv[c]; }
    const float inv = 1.f / z;

    float oa[16] = {};
#pragma unroll
    for (int c = 0; c < 11; ++c) {
      int cj = cols[c] < 0 ? 0 : cols[c];
      const bf16* vrow = v + bb + (size_t)cj * DM + eo;
      bf16x8 vv0 = *(const bf16x8*)(vrow);
      bf16x8 vv1 = *(const bf16x8*)(vrow + 8);
#pragma unroll
      for (int e = 0; e < 8; ++e) {
        oa[e]     += sv[c] * (float)vv0[e];
        oa[8 + e] += sv[c] * (float)vv1[e];
      }
    }
    bf16x8 ov0, ov1;
#pragma unroll
    for (int e = 0; e < 8; ++e) {
      ov0[e] = (bf16)(oa[e] * inv);
      ov1[e] = (bf16)(oa[8 + e] * inv);
    }
    bf16* orow = o + bb + (size_t)i * DM + eo;
    *(bf16x8*)(orow) = ov0;
    *(bf16x8*)(orow + 8) = ov1;
    return;
  }

  // ---- row-0 partial: (b, h, chunk of 256 cols) ----
  const int idx = blockIdx.x - 1024;    // 0..255
  const int b = idx >> 7;
  const int rem = idx & 127;
  const int h = rem >> 3;
  const int c = rem & 7;
  const size_t hb = (size_t)b * SEQ_L * DM + (size_t)h * HD;
  const int j = c * 256 + t;

  bf16x8 qv8[8];
#pragma unroll
  for (int cc = 0; cc < 8; ++cc) qv8[cc] = *(const bf16x8*)(q + hb + cc * 8);

  float acc = 0.f;
#pragma unroll
  for (int cc = 0; cc < 8; ++cc) {
    bf16x8 kv = *(const bf16x8*)(k + hb + (size_t)j * DM + cc * 8);
#pragma unroll
    for (int e = 0; e < 8; ++e) acc += (float)qv8[cc][e] * (float)kv[e];
  }
  float s = acc * 0.125f;
  float mloc = s;
#pragma unroll
  for (int off = 32; off > 0; off >>= 1) mloc = fmaxf(mloc, __shfl_xor(mloc, off));
  if (lane == 0) redm[w] = mloc;
  __syncthreads();
  const float m = fmaxf(fmaxf(redm[0], redm[1]), fmaxf(redm[2], redm[3]));

  float e = __expf(s - m);
  sbuf[t] = e;
  float zloc = e;
#pragma unroll
  for (int off = 32; off > 0; off >>= 1) zloc += __shfl_xor(zloc, off);
  if (lane == 0) redz[w] = zloc;
  __syncthreads();
  const float zc = redz[0] + redz[1] + redz[2] + redz[3];

  float oa = 0.f;
  for (int jj = w; jj < 256; jj += 4)
    oa += sbuf[jj] * (float)v[hb + (size_t)(c * 256 + jj) * DM + lane];
  part[w][lane] = oa;
  __syncthreads();
  if (t < 64) pv[idx * 64 + t] = part[0][t] + part[1][t] + part[2][t] + part[3][t];
  if (t == 0) { pm[idx] = m; pz[idx] = zc; }
}

// ---------------- launch ----------------
extern "C" void kernel_launch(void* const* d_in, const int* in_sizes, int n_in,
                              void* d_out, int out_size, void* d_ws, size_t ws_size,
                              hipStream_t stream) {
  const float* x     = (const float*)d_in[0];
  const float* freqs = (const float*)d_in[1];
  const float* wq    = (const float*)d_in[2];
  const float* wk    = (const float*)d_in[3];
  const float* wv    = (const float*)d_in[4];
  const float* wo    = (const float*)d_in[5];
  float* out = (float*)d_out;

  char* ws = (char*)d_ws;
  bf16* xb  = (bf16*)(ws + 0);          // 8 MiB
  bf16* wqb = (bf16*)(ws + 8388608);    // 2 MiB each
  bf16* wkb = (bf16*)(ws + 10485760);
  bf16* wvb = (bf16*)(ws + 12582912);
  bf16* wob = (bf16*)(ws + 14680064);
  bf16* qb  = (bf16*)(ws + 16777216);   // 8 MiB [B,L,H,HD]
  bf16* kb  = (bf16*)(ws + 25165824);
  bf16* vb  = (bf16*)(ws + 33554432);
  bf16* ab  = (bf16*)(ws + 41943040);   // 8 MiB; end 48 MiB
  int*    ctab = (int*)(ws + 50331648); // 96 KB
  float*  pm   = (float*)(ws + 50462720);
  float*  pz   = (float*)(ws + 50463744);
  float*  pv   = (float*)(ws + 50464768);   // 64 KB
  float2* rtab = (float2*)(ws + 50593792);  // 512 KB rope cos/sin table
  (void)ws_size;

  prep_kernel<<<8456, 256, 0, stream>>>(x, wq, wk, wv, wo, freqs, xb, wqb, wkb, wvb, wob, ctab, rtab);
  qkv_gemm_kernel<<<dim3(32, 8, 3), 256, 0, stream>>>(xb, wqb, wkb, wvb, qb, kb, vb, rtab);
  attn_kernel<<<dim3(1280, 1), 256, 0, stream>>>(qb, kb, vb, ab, ctab, pm, pz, pv);
  out_gemm_kernel<<<dim3(64, 8), 256, 0, stream>>>(ab, wob, out, pm, pz, pv);
}

// Round 10
// 164.646 us; speedup vs baseline: 10.0204x; 1.0380x over previous
//
#include <hip/hip_runtime.h>
#include <math.h>

#define SEQ_L 2048
#define DM 1024
#define NH 16
#define HD 64
#define NB 2
#define KD 1024   // GEMM K
#define ND 1024   // GEMM N

typedef __bf16 bf16;
typedef __bf16 bf16x8 __attribute__((ext_vector_type(8)));
typedef __bf16 bf16x4 __attribute__((ext_vector_type(4)));
typedef __bf16 bf16x2 __attribute__((ext_vector_type(2)));
typedef float f32x4 __attribute__((ext_vector_type(4)));

// ---------------- jax threefry2x32, key = (0, 42); partitionable random_bits ----------------
__device__ inline uint32_t rotl32(uint32_t v, int n) { return (v << n) | (v >> (32 - n)); }

__device__ inline void threefry(uint32_t x0, uint32_t x1, uint32_t* o0, uint32_t* o1) {
  const uint32_t ks0 = 0u, ks1 = 42u, ks2 = 0u ^ 42u ^ 0x1BD11BDAu;
  x0 += ks0; x1 += ks1;
#define TF_R(rr) { x0 += x1; x1 = rotl32(x1, rr); x1 ^= x0; }
  TF_R(13) TF_R(15) TF_R(26) TF_R(6)
  x0 += ks1; x1 += ks2 + 1u;
  TF_R(17) TF_R(29) TF_R(16) TF_R(24)
  x0 += ks2; x1 += ks0 + 2u;
  TF_R(13) TF_R(15) TF_R(26) TF_R(6)
  x0 += ks0; x1 += ks1 + 3u;
  TF_R(17) TF_R(29) TF_R(16) TF_R(24)
  x0 += ks1; x1 += ks2 + 4u;
  TF_R(13) TF_R(15) TF_R(26) TF_R(6)
  x0 += ks2; x1 += ks0 + 5u;
#undef TF_R
  *o0 = x0; *o1 = x1;
}

// jax_threefry_partitionable=True: counter (hi=0, lo=flat_idx), bits = o0 ^ o1.
__device__ inline int rand_col(int i, int s) {
  uint32_t o0, o1;
  threefry(0u, (uint32_t)(2 * i + s), &o0, &o1);
  uint32_t bits = o0 ^ o1;
  float u = __uint_as_float((bits >> 9) | 0x3f800000u) - 1.0f;
  return (int)floorf(u * (float)(i + 1));
}

// ---------------- prep: conversions + ctab + rope cos/sin table ----------------
__global__ void prep_kernel(const float* __restrict__ x,
                            const float* __restrict__ w0, const float* __restrict__ w1,
                            const float* __restrict__ w2, const float* __restrict__ w3,
                            const float* __restrict__ freqs,
                            bf16* __restrict__ xb,
                            bf16* __restrict__ o0, bf16* __restrict__ o1,
                            bf16* __restrict__ o2, bf16* __restrict__ o3,
                            int* __restrict__ ctab, float2* __restrict__ rtab) {
  const int bx = blockIdx.x;
  const int t = threadIdx.x;
  if (bx < 8192) {
    const float* src;
    bf16* dst;
    int idx;
    if (bx < 4096) { src = x; dst = xb; idx = bx * 256 + t; }
    else {
      int widx = bx - 4096;
      int wsel = widx >> 10;
      switch (wsel) {
        case 0: src = w0; dst = o0; break;
        case 1: src = w1; dst = o1; break;
        case 2: src = w2; dst = o2; break;
        default: src = w3; dst = o3; break;
      }
      idx = (widx & 1023) * 256 + t;
    }
    float4 vv = ((const float4*)src)[idx];
    bf16x4 ov;
    ov[0] = (bf16)vv.x; ov[1] = (bf16)vv.y; ov[2] = (bf16)vv.z; ov[3] = (bf16)vv.w;
    *(bf16x4*)(dst + (size_t)idx * 4) = ov;
    return;
  }
  if (bx < 8200) {
    const int i = (bx - 8192) * 256 + t;    // 0..2047
    int cols[11]; int nc = 0;
    if (i >= 1) {
      int lo = i - 7; if (lo < 0) lo = 0;
      for (int j = lo; j <= i; ++j) cols[nc++] = j;
      if (lo > 0) cols[nc++] = 0;
#pragma unroll
      for (int s = 0; s < 2; ++s) {
        int rj = rand_col(i, s);
        bool dup = false;
        for (int c2 = 0; c2 < nc; ++c2) dup |= (cols[c2] == rj);
        if (!dup) cols[nc++] = rj;
      }
    }
    for (int c2 = nc; c2 < 11; ++c2) cols[c2] = -1;
#pragma unroll
    for (int c2 = 0; c2 < 11; ++c2) ctab[i * 12 + c2] = cols[c2];
    ctab[i * 12 + 11] = nc;
    return;
  }
  const int idx = (bx - 8200) * 256 + t;    // 0..65535
  float s, c;
  sincosf(freqs[idx], &s, &c);
  rtab[idx] = make_float2(c, s);
}

// ---------------- GEMM common ----------------
__device__ inline void gld16(const bf16* g, bf16* l) {
  __builtin_amdgcn_global_load_lds((const __attribute__((address_space(1))) void*)g,
                                   (__attribute__((address_space(3))) void*)l, 16, 0, 0);
}

// 128x128 tile, BK=64, XOR-swizzled LDS, pair-packed bf16 epilogue with optional fused RoPE.
__device__ inline void gemm_bt_body(const bf16* __restrict__ A, const bf16* __restrict__ W,
                                    bf16* __restrict__ C, const float2* __restrict__ rtab) {
  __shared__ __align__(16) bf16 As[128 * 64];   // 16 KB
  __shared__ __align__(16) bf16 Bs[128 * 64];   // 16 KB
  const int t = threadIdx.x;
  const int lane = t & 63;
  const int wave = t >> 6;
  const int wm = (wave >> 1) * 64;
  const int wn = (wave & 1) * 64;
  const int m0 = blockIdx.x * 128;
  const int n0 = blockIdx.y * 128;
  const int l15 = lane & 15;
  const int kq = lane >> 4;          // 0..3

  f32x4 acc[4][4] = {};

  for (int k0 = 0; k0 < KD; k0 += 64) {
#pragma unroll
    for (int n = 0; n < 4; ++n) {
      const int s = n * 256 + t;               // 16B slot; lane-contiguous per wave
      const int row = s >> 3;                  // 0..127
      const int ch = (s & 7) ^ (row & 7);      // XOR bank swizzle
      gld16(A + (size_t)(m0 + row) * KD + k0 + ch * 8, As + s * 8);
      gld16(W + (size_t)(n0 + row) * KD + k0 + ch * 8, Bs + s * 8);
    }
    __syncthreads();
#pragma unroll
    for (int ks = 0; ks < 2; ++ks) {
      const int cb = ks * 4 + kq;              // k-chunk 0..7
      bf16x8 af[4], bfr[4];
#pragma unroll
      for (int mt = 0; mt < 4; ++mt) {
        const int row = wm + mt * 16 + l15;
        af[mt] = *(const bf16x8*)(As + row * 64 + ((cb ^ (row & 7)) * 8));
      }
#pragma unroll
      for (int nt = 0; nt < 4; ++nt) {
        const int row = wn + nt * 16 + l15;
        bfr[nt] = *(const bf16x8*)(Bs + row * 64 + ((cb ^ (row & 7)) * 8));
      }
#pragma unroll
      for (int mt = 0; mt < 4; ++mt)
#pragma unroll
        for (int nt = 0; nt < 4; ++nt)
          acc[mt][nt] = __builtin_amdgcn_mfma_f32_16x16x32_bf16(af[mt], bfr[nt], acc[mt][nt], 0, 0, 0);
    }
    __syncthreads();
  }
  // C/D layout: col = lane&15, row = (lane>>4)*4 + reg   [verified m89]
  const int colb = n0 + wn + l15;
  const int rowb = m0 + wm + (lane >> 4) * 4;
  const int odd = l15 & 1;
#pragma unroll
  for (int mt = 0; mt < 4; ++mt)
#pragma unroll
    for (int nt = 0; nt < 4; ++nt) {
      const int col = colb + nt * 16;
      const int jj = (col & 63) >> 1;
#pragma unroll
      for (int rr = 0; rr < 4; ++rr) {
        float val = acc[mt][nt][rr];
        float other = __shfl_xor(val, 1);      // partner column value
        if (!odd) {
          const int row = rowb + mt * 16 + rr;
          float lo, hi;
          if (rtab) {
            float2 cs = rtab[(row & (SEQ_L - 1)) * 32 + jj];
            lo = val * cs.x - other * cs.y;    // out_re
            hi = val * cs.y + other * cs.x;    // out_im
          } else { lo = val; hi = other; }
          bf16x2 p; p[0] = (bf16)lo; p[1] = (bf16)hi;
          *(bf16x2*)(C + (size_t)row * ND + col) = p;
        }
      }
    }
}

// grid (32,8,3) = 768 blocks; 3 blocks/CU
__global__ __launch_bounds__(256, 3) void qkv_gemm_kernel(
    const bf16* __restrict__ xb, const bf16* __restrict__ wqb, const bf16* __restrict__ wkb,
    const bf16* __restrict__ wvb, bf16* __restrict__ qb, bf16* __restrict__ kb, bf16* __restrict__ vb,
    const float2* __restrict__ rtab) {
  const bf16* W = blockIdx.z == 0 ? wqb : blockIdx.z == 1 ? wkb : wvb;
  bf16* O = blockIdx.z == 0 ? qb : blockIdx.z == 1 ? kb : vb;
  const float2* rt = blockIdx.z < 2 ? rtab : nullptr;   // rope on q,k only
  gemm_bt_body(xb, W, O, rt);
}

// ---- out-projection GEMM: 64x128 tile, BK=64, swizzled; grid (64,8) = 512 blocks ----
// Blocks x==0 / x==32 first materialize row-0 attention output from (pm,pz,pv).
__global__ __launch_bounds__(256, 2) void out_gemm_kernel(
    bf16* __restrict__ ab, const bf16* __restrict__ wob, float* __restrict__ out,
    const float* __restrict__ pm, const float* __restrict__ pz, const float* __restrict__ pv) {
  const int t = threadIdx.x;
  const int m0 = blockIdx.x * 64;
  const int n0 = blockIdx.y * 128;

  if (blockIdx.x == 0 || blockIdx.x == 32) {
    const int b = blockIdx.x == 0 ? 0 : 1;
#pragma unroll
    for (int e = t; e < DM; e += 256) {
      const int h = e >> 6, d = e & 63;
      const int base = b * 128 + h * 8;
      float M = -1e30f;
#pragma unroll
      for (int c = 0; c < 8; ++c) M = fmaxf(M, pm[base + c]);
      float Z = 0.f, od = 0.f;
#pragma unroll
      for (int c = 0; c < 8; ++c) {
        float sc = __expf(pm[base + c] - M);
        Z += pz[base + c] * sc;
        od += pv[(base + c) * 64 + d] * sc;
      }
      ab[(size_t)b * SEQ_L * DM + e] = (bf16)(od / Z);
    }
    __syncthreads();   // drain stores before staging reads the same row
  }

  __shared__ __align__(16) bf16 As[64 * 64];    // 8 KB
  __shared__ __align__(16) bf16 Bs[128 * 64];   // 16 KB
  const int lane = t & 63;
  const int wave = t >> 6;
  const int wm = (wave >> 1) * 32;
  const int wn = (wave & 1) * 64;
  const int l15 = lane & 15;
  const int kq = lane >> 4;

  f32x4 acc[2][4] = {};

  for (int k0 = 0; k0 < KD; k0 += 64) {
#pragma unroll
    for (int n = 0; n < 2; ++n) {
      const int s = n * 256 + t;               // 512 slots for As
      const int row = s >> 3;                  // 0..63
      const int ch = (s & 7) ^ (row & 7);
      gld16(ab + (size_t)(m0 + row) * KD + k0 + ch * 8, As + s * 8);
    }
#pragma unroll
    for (int n = 0; n < 4; ++n) {
      const int s = n * 256 + t;               // 1024 slots for Bs
      const int row = s >> 3;                  // 0..127
      const int ch = (s & 7) ^ (row & 7);
      gld16(wob + (size_t)(n0 + row) * KD + k0 + ch * 8, Bs + s * 8);
    }
    __syncthreads();
#pragma unroll
    for (int ks = 0; ks < 2; ++ks) {
      const int cb = ks * 4 + kq;
      bf16x8 af[2], bfr[4];
#pragma unroll
      for (int mt = 0; mt < 2; ++mt) {
        const int row = wm + mt * 16 + l15;
        af[mt] = *(const bf16x8*)(As + row * 64 + ((cb ^ (row & 7)) * 8));
      }
#pragma unroll
      for (int nt = 0; nt < 4; ++nt) {
        const int row = wn + nt * 16 + l15;
        bfr[nt] = *(const bf16x8*)(Bs + row * 64 + ((cb ^ (row & 7)) * 8));
      }
#pragma unroll
      for (int mt = 0; mt < 2; ++mt)
#pragma unroll
        for (int nt = 0; nt < 4; ++nt)
          acc[mt][nt] = __builtin_amdgcn_mfma_f32_16x16x32_bf16(af[mt], bfr[nt], acc[mt][nt], 0, 0, 0);
    }
    __syncthreads();
  }
  const int colb = n0 + wn + l15;
  const int rowb = m0 + wm + (lane >> 4) * 4;
#pragma unroll
  for (int mt = 0; mt < 2; ++mt)
#pragma unroll
    for (int nt = 0; nt < 4; ++nt)
#pragma unroll
      for (int rr = 0; rr < 4; ++rr)
        out[(size_t)(rowb + mt * 16 + rr) * ND + colb + nt * 16] = acc[mt][nt][rr];
}

// ---------------- attention ----------------
// grid (1280, 1), 256 threads.
//  bx < 256  : row-0 partials per (b, h, 256-col chunk) -> pm/pz/pv (dispatched FIRST: no tail).
//  bx >= 256 : sparse rows; wave handles one row i for ALL 16 heads (2KB wave-loads);
//              ALL 44 k+v load-quads prefetched into registers before any use (ILP).
__global__ __launch_bounds__(256, 2) void attn_kernel(const bf16* __restrict__ q, const bf16* __restrict__ k,
                                                      const bf16* __restrict__ v, bf16* __restrict__ o,
                                                      const int* __restrict__ ctab,
                                                      float* __restrict__ pm, float* __restrict__ pz,
                                                      float* __restrict__ pv) {
  const int t = threadIdx.x;
  const int lane = t & 63;
  const int w = t >> 6;

  __shared__ float sbuf[256];
  __shared__ float redm[4], redz[4];
  __shared__ float part[4][64];

  if (blockIdx.x >= 256) {
    const int sbx = blockIdx.x - 256;               // 0..1023
    const int b = sbx >> 9;
    const int tt = sbx & 511;
    const int tile = ((tt & 7) << 6) + (tt >> 3);   // XCD swizzle
    const int i = tile * 4 + 1 + w;
    if (i >= SEQ_L) return;   // wave-uniform
    const size_t bb = (size_t)b * SEQ_L * DM;
    const int eo = lane * 16;

    const bf16* qrow = q + bb + (size_t)i * DM + eo;
    bf16x8 qv0 = *(const bf16x8*)(qrow);
    bf16x8 qv1 = *(const bf16x8*)(qrow + 8);

    const int4* cp = (const int4*)(ctab + i * 12);
    int4 ca = cp[0], cb = cp[1], cc = cp[2];
    int cols[11] = {ca.x, ca.y, ca.z, ca.w, cb.x, cb.y, cb.z, cb.w, cc.x, cc.y, cc.z};

    // prefetch ALL k and v rows into registers (44 independent 16B loads in flight)
    bf16x8 kv[11][2], vv[11][2];
#pragma unroll
    for (int c = 0; c < 11; ++c) {
      int cj = cols[c] < 0 ? 0 : cols[c];
      const bf16* krow = k + bb + (size_t)cj * DM + eo;
      kv[c][0] = *(const bf16x8*)(krow);
      kv[c][1] = *(const bf16x8*)(krow + 8);
    }
#pragma unroll
    for (int c = 0; c < 11; ++c) {
      int cj = cols[c] < 0 ? 0 : cols[c];
      const bf16* vrow = v + bb + (size_t)cj * DM + eo;
      vv[c][0] = *(const bf16x8*)(vrow);
      vv[c][1] = *(const bf16x8*)(vrow + 8);
    }

    float sv[11];
#pragma unroll
    for (int c = 0; c < 11; ++c) {
      float acc = 0.f;
#pragma unroll
      for (int e = 0; e < 8; ++e)
        acc += (float)qv0[e] * (float)kv[c][0][e] + (float)qv1[e] * (float)kv[c][1][e];
      sv[c] = acc;
    }
#pragma unroll
    for (int c = 0; c < 11; ++c) {
      sv[c] += __shfl_xor(sv[c], 1);
      sv[c] += __shfl_xor(sv[c], 2);
      sv[c] = cols[c] < 0 ? -1e30f : sv[c] * 0.125f;
    }
    float m = -1e30f;
#pragma unroll
    for (int c = 0; c < 11; ++c) m = fmaxf(m, sv[c]);
    float z = 0.f;
#pragma unroll
    for (int c = 0; c < 11; ++c) { sv[c] = __expf(sv[c] - m); z += sv[c]; }
    const float inv = 1.f / z;

    float oa[16] = {};
#pragma unroll
    for (int c = 0; c < 11; ++c) {
#pragma unroll
      for (int e = 0; e < 8; ++e) {
        oa[e]     += sv[c] * (float)vv[c][0][e];
        oa[8 + e] += sv[c] * (float)vv[c][1][e];
      }
    }
    bf16x8 ov0, ov1;
#pragma unroll
    for (int e = 0; e < 8; ++e) {
      ov0[e] = (bf16)(oa[e] * inv);
      ov1[e] = (bf16)(oa[8 + e] * inv);
    }
    bf16* orow = o + bb + (size_t)i * DM + eo;
    *(bf16x8*)(orow) = ov0;
    *(bf16x8*)(orow + 8) = ov1;
    return;
  }

  // ---- row-0 partial: (b, h, chunk of 256 cols) ----
  const int idx = blockIdx.x;           // 0..255
  const int b = idx >> 7;
  const int rem = idx & 127;
  const int h = rem >> 3;
  const int c = rem & 7;
  const size_t hb = (size_t)b * SEQ_L * DM + (size_t)h * HD;
  const int j = c * 256 + t;

  bf16x8 qv8[8];
#pragma unroll
  for (int cc = 0; cc < 8; ++cc) qv8[cc] = *(const bf16x8*)(q + hb + cc * 8);

  float acc = 0.f;
#pragma unroll
  for (int cc = 0; cc < 8; ++cc) {
    bf16x8 kv = *(const bf16x8*)(k + hb + (size_t)j * DM + cc * 8);
#pragma unroll
    for (int e = 0; e < 8; ++e) acc += (float)qv8[cc][e] * (float)kv[e];
  }
  float s = acc * 0.125f;
  float mloc = s;
#pragma unroll
  for (int off = 32; off > 0; off >>= 1) mloc = fmaxf(mloc, __shfl_xor(mloc, off));
  if (lane == 0) redm[w] = mloc;
  __syncthreads();
  const float m = fmaxf(fmaxf(redm[0], redm[1]), fmaxf(redm[2], redm[3]));

  float e = __expf(s - m);
  sbuf[t] = e;
  float zloc = e;
#pragma unroll
  for (int off = 32; off > 0; off >>= 1) zloc += __shfl_xor(zloc, off);
  if (lane == 0) redz[w] = zloc;
  __syncthreads();
  const float zc = redz[0] + redz[1] + redz[2] + redz[3];

  float oa = 0.f;
  for (int jj = w; jj < 256; jj += 4)
    oa += sbuf[jj] * (float)v[hb + (size_t)(c * 256 + jj) * DM + lane];
  part[w][lane] = oa;
  __syncthreads();
  if (t < 64) pv[idx * 64 + t] = part[0][t] + part[1][t] + part[2][t] + part[3][t];
  if (t == 0) { pm[idx] = m; pz[idx] = zc; }
}

// ---------------- launch ----------------
extern "C" void kernel_launch(void* const* d_in, const int* in_sizes, int n_in,
                              void* d_out, int out_size, void* d_ws, size_t ws_size,
                              hipStream_t stream) {
  const float* x     = (const float*)d_in[0];
  const float* freqs = (const float*)d_in[1];
  const float* wq    = (const float*)d_in[2];
  const float* wk    = (const float*)d_in[3];
  const float* wv    = (const float*)d_in[4];
  const float* wo    = (const float*)d_in[5];
  float* out = (float*)d_out;

  char* ws = (char*)d_ws;
  bf16* xb  = (bf16*)(ws + 0);          // 8 MiB
  bf16* wqb = (bf16*)(ws + 8388608);    // 2 MiB each
  bf16* wkb = (bf16*)(ws + 10485760);
  bf16* wvb = (bf16*)(ws + 12582912);
  bf16* wob = (bf16*)(ws + 14680064);
  bf16* qb  = (bf16*)(ws + 16777216);   // 8 MiB [B,L,H,HD]
  bf16* kb  = (bf16*)(ws + 25165824);
  bf16* vb  = (bf16*)(ws + 33554432);
  bf16* ab  = (bf16*)(ws + 41943040);   // 8 MiB; end 48 MiB
  int*    ctab = (int*)(ws + 50331648); // 96 KB
  float*  pm   = (float*)(ws + 50462720);
  float*  pz   = (float*)(ws + 50463744);
  float*  pv   = (float*)(ws + 50464768);   // 64 KB
  float2* rtab = (float2*)(ws + 50593792);  // 512 KB rope cos/sin table
  (void)ws_size;

  prep_kernel<<<8456, 256, 0, stream>>>(x, wq, wk, wv, wo, freqs, xb, wqb, wkb, wvb, wob, ctab, rtab);
  qkv_gemm_kernel<<<dim3(32, 8, 3), 256, 0, stream>>>(xb, wqb, wkb, wvb, qb, kb, vb, rtab);
  attn_kernel<<<dim3(1280, 1), 256, 0, stream>>>(qb, kb, vb, ab, ctab, pm, pz, pv);
  out_gemm_kernel<<<dim3(64, 8), 256, 0, stream>>>(ab, wob, out, pm, pz, pv);
}

// Round 11
// 161.336 us; speedup vs baseline: 10.2260x; 1.0205x over previous
//
#include <hip/hip_runtime.h>
#include <math.h>

#define SEQ_L 2048
#define DM 1024
#define NH 16
#define HD 64
#define NB 2
#define KD 1024   // GEMM K
#define ND 1024   // GEMM N

typedef __bf16 bf16;
typedef __bf16 bf16x8 __attribute__((ext_vector_type(8)));
typedef __bf16 bf16x4 __attribute__((ext_vector_type(4)));
typedef __bf16 bf16x2 __attribute__((ext_vector_type(2)));
typedef float f32x4 __attribute__((ext_vector_type(4)));

// ---------------- jax threefry2x32, key = (0, 42); partitionable random_bits ----------------
__device__ inline uint32_t rotl32(uint32_t v, int n) { return (v << n) | (v >> (32 - n)); }

__device__ inline void threefry(uint32_t x0, uint32_t x1, uint32_t* o0, uint32_t* o1) {
  const uint32_t ks0 = 0u, ks1 = 42u, ks2 = 0u ^ 42u ^ 0x1BD11BDAu;
  x0 += ks0; x1 += ks1;
#define TF_R(rr) { x0 += x1; x1 = rotl32(x1, rr); x1 ^= x0; }
  TF_R(13) TF_R(15) TF_R(26) TF_R(6)
  x0 += ks1; x1 += ks2 + 1u;
  TF_R(17) TF_R(29) TF_R(16) TF_R(24)
  x0 += ks2; x1 += ks0 + 2u;
  TF_R(13) TF_R(15) TF_R(26) TF_R(6)
  x0 += ks0; x1 += ks1 + 3u;
  TF_R(17) TF_R(29) TF_R(16) TF_R(24)
  x0 += ks1; x1 += ks2 + 4u;
  TF_R(13) TF_R(15) TF_R(26) TF_R(6)
  x0 += ks2; x1 += ks0 + 5u;
#undef TF_R
  *o0 = x0; *o1 = x1;
}

// jax_threefry_partitionable=True: counter (hi=0, lo=flat_idx), bits = o0 ^ o1.
__device__ inline int rand_col(int i, int s) {
  uint32_t o0, o1;
  threefry(0u, (uint32_t)(2 * i + s), &o0, &o1);
  uint32_t bits = o0 ^ o1;
  float u = __uint_as_float((bits >> 9) | 0x3f800000u) - 1.0f;
  return (int)floorf(u * (float)(i + 1));
}

// ---------------- prep: conversions + ctab + rope cos/sin table ----------------
__global__ void prep_kernel(const float* __restrict__ x,
                            const float* __restrict__ w0, const float* __restrict__ w1,
                            const float* __restrict__ w2, const float* __restrict__ w3,
                            const float* __restrict__ freqs,
                            bf16* __restrict__ xb,
                            bf16* __restrict__ o0, bf16* __restrict__ o1,
                            bf16* __restrict__ o2, bf16* __restrict__ o3,
                            int* __restrict__ ctab, float2* __restrict__ rtab) {
  const int bx = blockIdx.x;
  const int t = threadIdx.x;
  if (bx < 8192) {
    const float* src;
    bf16* dst;
    int idx;
    if (bx < 4096) { src = x; dst = xb; idx = bx * 256 + t; }
    else {
      int widx = bx - 4096;
      int wsel = widx >> 10;
      switch (wsel) {
        case 0: src = w0; dst = o0; break;
        case 1: src = w1; dst = o1; break;
        case 2: src = w2; dst = o2; break;
        default: src = w3; dst = o3; break;
      }
      idx = (widx & 1023) * 256 + t;
    }
    float4 vv = ((const float4*)src)[idx];
    bf16x4 ov;
    ov[0] = (bf16)vv.x; ov[1] = (bf16)vv.y; ov[2] = (bf16)vv.z; ov[3] = (bf16)vv.w;
    *(bf16x4*)(dst + (size_t)idx * 4) = ov;
    return;
  }
  if (bx < 8200) {
    const int i = (bx - 8192) * 256 + t;    // 0..2047
    int cols[11]; int nc = 0;
    if (i >= 1) {
      int lo = i - 7; if (lo < 0) lo = 0;
      for (int j = lo; j <= i; ++j) cols[nc++] = j;
      if (lo > 0) cols[nc++] = 0;
#pragma unroll
      for (int s = 0; s < 2; ++s) {
        int rj = rand_col(i, s);
        bool dup = false;
        for (int c2 = 0; c2 < nc; ++c2) dup |= (cols[c2] == rj);
        if (!dup) cols[nc++] = rj;
      }
    }
    for (int c2 = nc; c2 < 11; ++c2) cols[c2] = -1;
#pragma unroll
    for (int c2 = 0; c2 < 11; ++c2) ctab[i * 12 + c2] = cols[c2];
    ctab[i * 12 + 11] = nc;
    return;
  }
  const int idx = (bx - 8200) * 256 + t;    // 0..65535
  float s, c;
  sincosf(freqs[idx], &s, &c);
  rtab[idx] = make_float2(c, s);
}

// ---------------- GEMM common ----------------
__device__ inline void gld16(const bf16* g, bf16* l) {
  __builtin_amdgcn_global_load_lds((const __attribute__((address_space(1))) void*)g,
                                   (__attribute__((address_space(3))) void*)l, 16, 0, 0);
}

// ---- fused QKV GEMM: one block = 128(m) x 64(n) tile of q, k AND v (shared A staging).
// BK=64, XOR-swizzled LDS. grid (32,16) = 512 blocks = 2 blocks/CU, one residency pass.
__global__ __launch_bounds__(256, 2) void qkv_gemm_kernel(
    const bf16* __restrict__ xb, const bf16* __restrict__ wqb, const bf16* __restrict__ wkb,
    const bf16* __restrict__ wvb, bf16* __restrict__ qb, bf16* __restrict__ kb, bf16* __restrict__ vb,
    const float2* __restrict__ rtab) {
  __shared__ __align__(16) bf16 As[128 * 64];       // 16 KB
  __shared__ __align__(16) bf16 Bs[3][64 * 64];     // 24 KB
  const bf16* Ws[3] = {wqb, wkb, wvb};
  bf16* Ds[3] = {qb, kb, vb};

  const int t = threadIdx.x;
  const int lane = t & 63;
  const int w = t >> 6;
  const int wm = (w >> 1) * 64;     // m-offset of wave tile (64 rows)
  const int wn = (w & 1) * 32;      // n-offset of wave tile (32 cols)
  const int m0 = blockIdx.x * 128;
  const int n0 = blockIdx.y * 64;
  const int l15 = lane & 15;
  const int kq = lane >> 4;         // 0..3

  f32x4 acc[3][4][2] = {};

  for (int k0 = 0; k0 < KD; k0 += 64) {
    // A: 128x64 = 1024 slots of 16B; 4 per thread
#pragma unroll
    for (int n = 0; n < 4; ++n) {
      const int s = n * 256 + t;
      const int row = s >> 3;                  // 0..127
      const int ch = (s & 7) ^ (row & 7);      // XOR bank swizzle
      gld16(xb + (size_t)(m0 + row) * KD + k0 + ch * 8, As + s * 8);
    }
    // B_j: 64x64 = 512 slots each; 2 per thread per output
#pragma unroll
    for (int j = 0; j < 3; ++j)
#pragma unroll
      for (int n = 0; n < 2; ++n) {
        const int s = n * 256 + t;
        const int row = s >> 3;                // 0..63
        const int ch = (s & 7) ^ (row & 7);
        gld16(Ws[j] + (size_t)(n0 + row) * KD + k0 + ch * 8, &Bs[j][s * 8]);
      }
    __syncthreads();
#pragma unroll
    for (int ks = 0; ks < 2; ++ks) {
      const int cb = ks * 4 + kq;              // k-chunk 0..7
      bf16x8 af[4];
#pragma unroll
      for (int mt = 0; mt < 4; ++mt) {
        const int row = wm + mt * 16 + l15;
        af[mt] = *(const bf16x8*)(As + row * 64 + ((cb ^ (row & 7)) * 8));
      }
#pragma unroll
      for (int j = 0; j < 3; ++j) {
        bf16x8 bfr[2];
#pragma unroll
        for (int nt = 0; nt < 2; ++nt) {
          const int row = wn + nt * 16 + l15;
          bfr[nt] = *(const bf16x8*)(&Bs[j][row * 64 + ((cb ^ (row & 7)) * 8)]);
        }
#pragma unroll
        for (int mt = 0; mt < 4; ++mt)
#pragma unroll
          for (int nt = 0; nt < 2; ++nt)
            acc[j][mt][nt] = __builtin_amdgcn_mfma_f32_16x16x32_bf16(af[mt], bfr[nt], acc[j][mt][nt], 0, 0, 0);
      }
    }
    __syncthreads();
  }
  // C/D layout: col = lane&15, row = (lane>>4)*4 + reg   [verified m89]
  const int colb = n0 + wn + l15;
  const int rowb = m0 + wm + (lane >> 4) * 4;
  const int odd = l15 & 1;
#pragma unroll
  for (int j = 0; j < 3; ++j) {
    bf16* D = Ds[j];
    const bool dorope = (j < 2);
#pragma unroll
    for (int mt = 0; mt < 4; ++mt)
#pragma unroll
      for (int nt = 0; nt < 2; ++nt) {
        const int col = colb + nt * 16;
        const int jj = (col & 63) >> 1;
#pragma unroll
        for (int rr = 0; rr < 4; ++rr) {
          float val = acc[j][mt][nt][rr];
          float other = __shfl_xor(val, 1);    // partner column value
          if (!odd) {
            const int row = rowb + mt * 16 + rr;
            float lo, hi;
            if (dorope) {
              float2 cs = rtab[(row & (SEQ_L - 1)) * 32 + jj];
              lo = val * cs.x - other * cs.y;  // out_re
              hi = val * cs.y + other * cs.x;  // out_im
            } else { lo = val; hi = other; }
            bf16x2 p; p[0] = (bf16)lo; p[1] = (bf16)hi;
            *(bf16x2*)(D + (size_t)row * ND + col) = p;
          }
        }
      }
  }
}

// ---- out-projection GEMM: 64x128 tile, BK=64, swizzled; grid (64,8) = 512 blocks ----
// Blocks x==0 / x==32 first materialize row-0 attention output from (pm,pz,pv).
__global__ __launch_bounds__(256, 2) void out_gemm_kernel(
    bf16* __restrict__ ab, const bf16* __restrict__ wob, float* __restrict__ out,
    const float* __restrict__ pm, const float* __restrict__ pz, const float* __restrict__ pv) {
  const int t = threadIdx.x;
  const int m0 = blockIdx.x * 64;
  const int n0 = blockIdx.y * 128;

  if (blockIdx.x == 0 || blockIdx.x == 32) {
    const int b = blockIdx.x == 0 ? 0 : 1;
#pragma unroll
    for (int e = t; e < DM; e += 256) {
      const int h = e >> 6, d = e & 63;
      const int base = b * 128 + h * 8;
      float M = -1e30f;
#pragma unroll
      for (int c = 0; c < 8; ++c) M = fmaxf(M, pm[base + c]);
      float Z = 0.f, od = 0.f;
#pragma unroll
      for (int c = 0; c < 8; ++c) {
        float sc = __expf(pm[base + c] - M);
        Z += pz[base + c] * sc;
        od += pv[(base + c) * 64 + d] * sc;
      }
      ab[(size_t)b * SEQ_L * DM + e] = (bf16)(od / Z);
    }
    __syncthreads();   // drain stores before staging reads the same row
  }

  __shared__ __align__(16) bf16 As[64 * 64];    // 8 KB
  __shared__ __align__(16) bf16 Bs[128 * 64];   // 16 KB
  const int lane = t & 63;
  const int wave = t >> 6;
  const int wm = (wave >> 1) * 32;
  const int wn = (wave & 1) * 64;
  const int l15 = lane & 15;
  const int kq = lane >> 4;

  f32x4 acc[2][4] = {};

  for (int k0 = 0; k0 < KD; k0 += 64) {
#pragma unroll
    for (int n = 0; n < 2; ++n) {
      const int s = n * 256 + t;               // 512 slots for As
      const int row = s >> 3;                  // 0..63
      const int ch = (s & 7) ^ (row & 7);
      gld16(ab + (size_t)(m0 + row) * KD + k0 + ch * 8, As + s * 8);
    }
#pragma unroll
    for (int n = 0; n < 4; ++n) {
      const int s = n * 256 + t;               // 1024 slots for Bs
      const int row = s >> 3;                  // 0..127
      const int ch = (s & 7) ^ (row & 7);
      gld16(wob + (size_t)(n0 + row) * KD + k0 + ch * 8, Bs + s * 8);
    }
    __syncthreads();
#pragma unroll
    for (int ks = 0; ks < 2; ++ks) {
      const int cb = ks * 4 + kq;
      bf16x8 af[2], bfr[4];
#pragma unroll
      for (int mt = 0; mt < 2; ++mt) {
        const int row = wm + mt * 16 + l15;
        af[mt] = *(const bf16x8*)(As + row * 64 + ((cb ^ (row & 7)) * 8));
      }
#pragma unroll
      for (int nt = 0; nt < 4; ++nt) {
        const int row = wn + nt * 16 + l15;
        bfr[nt] = *(const bf16x8*)(Bs + row * 64 + ((cb ^ (row & 7)) * 8));
      }
#pragma unroll
      for (int mt = 0; mt < 2; ++mt)
#pragma unroll
        for (int nt = 0; nt < 4; ++nt)
          acc[mt][nt] = __builtin_amdgcn_mfma_f32_16x16x32_bf16(af[mt], bfr[nt], acc[mt][nt], 0, 0, 0);
    }
    __syncthreads();
  }
  const int colb = n0 + wn + l15;
  const int rowb = m0 + wm + (lane >> 4) * 4;
#pragma unroll
  for (int mt = 0; mt < 2; ++mt)
#pragma unroll
    for (int nt = 0; nt < 4; ++nt)
#pragma unroll
      for (int rr = 0; rr < 4; ++rr)
        out[(size_t)(rowb + mt * 16 + rr) * ND + colb + nt * 16] = acc[mt][nt][rr];
}

// ---------------- attention ----------------
// grid (1280, 1), 256 threads.
//  bx < 256  : row-0 partials per (b, h, 256-col chunk) -> pm/pz/pv (dispatched FIRST: no tail).
//  bx >= 256 : sparse rows; wave handles one row i for ALL 16 heads (2KB wave-loads);
//              ALL 44 k+v load-quads prefetched into registers before any use (ILP).
__global__ __launch_bounds__(256, 2) void attn_kernel(const bf16* __restrict__ q, const bf16* __restrict__ k,
                                                      const bf16* __restrict__ v, bf16* __restrict__ o,
                                                      const int* __restrict__ ctab,
                                                      float* __restrict__ pm, float* __restrict__ pz,
                                                      float* __restrict__ pv) {
  const int t = threadIdx.x;
  const int lane = t & 63;
  const int w = t >> 6;

  __shared__ float sbuf[256];
  __shared__ float redm[4], redz[4];
  __shared__ float part[4][64];

  if (blockIdx.x >= 256) {
    const int sbx = blockIdx.x - 256;               // 0..1023
    const int b = sbx >> 9;
    const int tt = sbx & 511;
    const int tile = ((tt & 7) << 6) + (tt >> 3);   // XCD swizzle
    const int i = tile * 4 + 1 + w;
    if (i >= SEQ_L) return;   // wave-uniform
    const size_t bb = (size_t)b * SEQ_L * DM;
    const int eo = lane * 16;

    const bf16* qrow = q + bb + (size_t)i * DM + eo;
    bf16x8 qv0 = *(const bf16x8*)(qrow);
    bf16x8 qv1 = *(const bf16x8*)(qrow + 8);

    const int4* cp = (const int4*)(ctab + i * 12);
    int4 ca = cp[0], cb = cp[1], cc = cp[2];
    int cols[11] = {ca.x, ca.y, ca.z, ca.w, cb.x, cb.y, cb.z, cb.w, cc.x, cc.y, cc.z};

    // prefetch ALL k and v rows into registers (44 independent 16B loads in flight)
    bf16x8 kv[11][2], vv[11][2];
#pragma unroll
    for (int c = 0; c < 11; ++c) {
      int cj = cols[c] < 0 ? 0 : cols[c];
      const bf16* krow = k + bb + (size_t)cj * DM + eo;
      kv[c][0] = *(const bf16x8*)(krow);
      kv[c][1] = *(const bf16x8*)(krow + 8);
    }
#pragma unroll
    for (int c = 0; c < 11; ++c) {
      int cj = cols[c] < 0 ? 0 : cols[c];
      const bf16* vrow = v + bb + (size_t)cj * DM + eo;
      vv[c][0] = *(const bf16x8*)(vrow);
      vv[c][1] = *(const bf16x8*)(vrow + 8);
    }

    float sv[11];
#pragma unroll
    for (int c = 0; c < 11; ++c) {
      float acc = 0.f;
#pragma unroll
      for (int e = 0; e < 8; ++e)
        acc += (float)qv0[e] * (float)kv[c][0][e] + (float)qv1[e] * (float)kv[c][1][e];
      sv[c] = acc;
    }
#pragma unroll
    for (int c = 0; c < 11; ++c) {
      sv[c] += __shfl_xor(sv[c], 1);
      sv[c] += __shfl_xor(sv[c], 2);
      sv[c] = cols[c] < 0 ? -1e30f : sv[c] * 0.125f;
    }
    float m = -1e30f;
#pragma unroll
    for (int c = 0; c < 11; ++c) m = fmaxf(m, sv[c]);
    float z = 0.f;
#pragma unroll
    for (int c = 0; c < 11; ++c) { sv[c] = __expf(sv[c] - m); z += sv[c]; }
    const float inv = 1.f / z;

    float oa[16] = {};
#pragma unroll
    for (int c = 0; c < 11; ++c) {
#pragma unroll
      for (int e = 0; e < 8; ++e) {
        oa[e]     += sv[c] * (float)vv[c][0][e];
        oa[8 + e] += sv[c] * (float)vv[c][1][e];
      }
    }
    bf16x8 ov0, ov1;
#pragma unroll
    for (int e = 0; e < 8; ++e) {
      ov0[e] = (bf16)(oa[e] * inv);
      ov1[e] = (bf16)(oa[8 + e] * inv);
    }
    bf16* orow = o + bb + (size_t)i * DM + eo;
    *(bf16x8*)(orow) = ov0;
    *(bf16x8*)(orow + 8) = ov1;
    return;
  }

  // ---- row-0 partial: (b, h, chunk of 256 cols) ----
  const int idx = blockIdx.x;           // 0..255
  const int b = idx >> 7;
  const int rem = idx & 127;
  const int h = rem >> 3;
  const int c = rem & 7;
  const size_t hb = (size_t)b * SEQ_L * DM + (size_t)h * HD;
  const int j = c * 256 + t;

  bf16x8 qv8[8];
#pragma unroll
  for (int cc = 0; cc < 8; ++cc) qv8[cc] = *(const bf16x8*)(q + hb + cc * 8);

  float acc = 0.f;
#pragma unroll
  for (int cc = 0; cc < 8; ++cc) {
    bf16x8 kv = *(const bf16x8*)(k + hb + (size_t)j * DM + cc * 8);
#pragma unroll
    for (int e = 0; e < 8; ++e) acc += (float)qv8[cc][e] * (float)kv[e];
  }
  float s = acc * 0.125f;
  float mloc = s;
#pragma unroll
  for (int off = 32; off > 0; off >>= 1) mloc = fmaxf(mloc, __shfl_xor(mloc, off));
  if (lane == 0) redm[w] = mloc;
  __syncthreads();
  const float m = fmaxf(fmaxf(redm[0], redm[1]), fmaxf(redm[2], redm[3]));

  float e = __expf(s - m);
  sbuf[t] = e;
  float zloc = e;
#pragma unroll
  for (int off = 32; off > 0; off >>= 1) zloc += __shfl_xor(zloc, off);
  if (lane == 0) redz[w] = zloc;
  __syncthreads();
  const float zc = redz[0] + redz[1] + redz[2] + redz[3];

  float oa = 0.f;
  for (int jj = w; jj < 256; jj += 4)
    oa += sbuf[jj] * (float)v[hb + (size_t)(c * 256 + jj) * DM + lane];
  part[w][lane] = oa;
  __syncthreads();
  if (t < 64) pv[idx * 64 + t] = part[0][t] + part[1][t] + part[2][t] + part[3][t];
  if (t == 0) { pm[idx] = m; pz[idx] = zc; }
}

// ---------------- launch ----------------
extern "C" void kernel_launch(void* const* d_in, const int* in_sizes, int n_in,
                              void* d_out, int out_size, void* d_ws, size_t ws_size,
                              hipStream_t stream) {
  const float* x     = (const float*)d_in[0];
  const float* freqs = (const float*)d_in[1];
  const float* wq    = (const float*)d_in[2];
  const float* wk    = (const float*)d_in[3];
  const float* wv    = (const float*)d_in[4];
  const float* wo    = (const float*)d_in[5];
  float* out = (float*)d_out;

  char* ws = (char*)d_ws;
  bf16* xb  = (bf16*)(ws + 0);          // 8 MiB
  bf16* wqb = (bf16*)(ws + 8388608);    // 2 MiB each
  bf16* wkb = (bf16*)(ws + 10485760);
  bf16* wvb = (bf16*)(ws + 12582912);
  bf16* wob = (bf16*)(ws + 14680064);
  bf16* qb  = (bf16*)(ws + 16777216);   // 8 MiB [B,L,H,HD]
  bf16* kb  = (bf16*)(ws + 25165824);
  bf16* vb  = (bf16*)(ws + 33554432);
  bf16* ab  = (bf16*)(ws + 41943040);   // 8 MiB; end 48 MiB
  int*    ctab = (int*)(ws + 50331648); // 96 KB
  float*  pm   = (float*)(ws + 50462720);
  float*  pz   = (float*)(ws + 50463744);
  float*  pv   = (float*)(ws + 50464768);   // 64 KB
  float2* rtab = (float2*)(ws + 50593792);  // 512 KB rope cos/sin table
  (void)ws_size;

  prep_kernel<<<8456, 256, 0, stream>>>(x, wq, wk, wv, wo, freqs, xb, wqb, wkb, wvb, wob, ctab, rtab);
  qkv_gemm_kernel<<<dim3(32, 16), 256, 0, stream>>>(xb, wqb, wkb, wvb, qb, kb, vb, rtab);
  attn_kernel<<<dim3(1280, 1), 256, 0, stream>>>(qb, kb, vb, ab, ctab, pm, pz, pv);
  out_gemm_kernel<<<dim3(64, 8), 256, 0, stream>>>(ab, wob, out, pm, pz, pv);
}

// Round 12
// 159.956 us; speedup vs baseline: 10.3142x; 1.0086x over previous
//
#include <hip/hip_runtime.h>
#include <math.h>

#define SEQ_L 2048
#define DM 1024
#define NH 16
#define HD 64
#define NB 2
#define KD 1024   // GEMM K
#define ND 1024   // GEMM N

typedef __bf16 bf16;
typedef __bf16 bf16x8 __attribute__((ext_vector_type(8)));
typedef __bf16 bf16x4 __attribute__((ext_vector_type(4)));
typedef __bf16 bf16x2 __attribute__((ext_vector_type(2)));
typedef float f32x4 __attribute__((ext_vector_type(4)));

// ---------------- jax threefry2x32, key = (0, 42); partitionable random_bits ----------------
__device__ inline uint32_t rotl32(uint32_t v, int n) { return (v << n) | (v >> (32 - n)); }

__device__ inline void threefry(uint32_t x0, uint32_t x1, uint32_t* o0, uint32_t* o1) {
  const uint32_t ks0 = 0u, ks1 = 42u, ks2 = 0u ^ 42u ^ 0x1BD11BDAu;
  x0 += ks0; x1 += ks1;
#define TF_R(rr) { x0 += x1; x1 = rotl32(x1, rr); x1 ^= x0; }
  TF_R(13) TF_R(15) TF_R(26) TF_R(6)
  x0 += ks1; x1 += ks2 + 1u;
  TF_R(17) TF_R(29) TF_R(16) TF_R(24)
  x0 += ks2; x1 += ks0 + 2u;
  TF_R(13) TF_R(15) TF_R(26) TF_R(6)
  x0 += ks0; x1 += ks1 + 3u;
  TF_R(17) TF_R(29) TF_R(16) TF_R(24)
  x0 += ks1; x1 += ks2 + 4u;
  TF_R(13) TF_R(15) TF_R(26) TF_R(6)
  x0 += ks2; x1 += ks0 + 5u;
#undef TF_R
  *o0 = x0; *o1 = x1;
}

// jax_threefry_partitionable=True: counter (hi=0, lo=flat_idx), bits = o0 ^ o1.
__device__ inline int rand_col(int i, int s) {
  uint32_t o0, o1;
  threefry(0u, (uint32_t)(2 * i + s), &o0, &o1);
  uint32_t bits = o0 ^ o1;
  float u = __uint_as_float((bits >> 9) | 0x3f800000u) - 1.0f;
  return (int)floorf(u * (float)(i + 1));
}

// ---------------- prep: conversions + ctab + rope cos/sin table ----------------
__global__ void prep_kernel(const float* __restrict__ x,
                            const float* __restrict__ w0, const float* __restrict__ w1,
                            const float* __restrict__ w2, const float* __restrict__ w3,
                            const float* __restrict__ freqs,
                            bf16* __restrict__ xb,
                            bf16* __restrict__ o0, bf16* __restrict__ o1,
                            bf16* __restrict__ o2, bf16* __restrict__ o3,
                            int* __restrict__ ctab, float2* __restrict__ rtab) {
  const int bx = blockIdx.x;
  const int t = threadIdx.x;
  if (bx < 8192) {
    const float* src;
    bf16* dst;
    int idx;
    if (bx < 4096) { src = x; dst = xb; idx = bx * 256 + t; }
    else {
      int widx = bx - 4096;
      int wsel = widx >> 10;
      switch (wsel) {
        case 0: src = w0; dst = o0; break;
        case 1: src = w1; dst = o1; break;
        case 2: src = w2; dst = o2; break;
        default: src = w3; dst = o3; break;
      }
      idx = (widx & 1023) * 256 + t;
    }
    float4 vv = ((const float4*)src)[idx];
    bf16x4 ov;
    ov[0] = (bf16)vv.x; ov[1] = (bf16)vv.y; ov[2] = (bf16)vv.z; ov[3] = (bf16)vv.w;
    *(bf16x4*)(dst + (size_t)idx * 4) = ov;
    return;
  }
  if (bx < 8200) {
    const int i = (bx - 8192) * 256 + t;    // 0..2047
    int cols[11]; int nc = 0;
    if (i >= 1) {
      int lo = i - 7; if (lo < 0) lo = 0;
      for (int j = lo; j <= i; ++j) cols[nc++] = j;
      if (lo > 0) cols[nc++] = 0;
#pragma unroll
      for (int s = 0; s < 2; ++s) {
        int rj = rand_col(i, s);
        bool dup = false;
        for (int c2 = 0; c2 < nc; ++c2) dup |= (cols[c2] == rj);
        if (!dup) cols[nc++] = rj;
      }
    }
    for (int c2 = nc; c2 < 11; ++c2) cols[c2] = -1;
#pragma unroll
    for (int c2 = 0; c2 < 11; ++c2) ctab[i * 12 + c2] = cols[c2];
    ctab[i * 12 + 11] = nc;
    return;
  }
  const int idx = (bx - 8200) * 256 + t;    // 0..65535
  float s, c;
  sincosf(freqs[idx], &s, &c);
  rtab[idx] = make_float2(c, s);
}

// ---------------- GEMM common ----------------
__device__ inline void gld16(const bf16* g, bf16* l) {
  __builtin_amdgcn_global_load_lds((const __attribute__((address_space(1))) void*)g,
                                   (__attribute__((address_space(3))) void*)l, 16, 0, 0);
}

// ---- fused QKV GEMM: one block = 64(m) x 64(n) tile of q, k AND v (shared A staging).
// BK=64, XOR-swizzled LDS, 32 KB total. grid (64,16) = 1024 blocks at 4 blocks/CU:
// 16 waves/CU in ONE residency pass (R11's 128x64 tile gave only 2 blocks/CU -> stall-bound).
__global__ __launch_bounds__(256, 4) void qkv_gemm_kernel(
    const bf16* __restrict__ xb, const bf16* __restrict__ wqb, const bf16* __restrict__ wkb,
    const bf16* __restrict__ wvb, bf16* __restrict__ qb, bf16* __restrict__ kb, bf16* __restrict__ vb,
    const float2* __restrict__ rtab) {
  __shared__ __align__(16) bf16 As[64 * 64];        // 8 KB
  __shared__ __align__(16) bf16 Bs[3][64 * 64];     // 24 KB
  const bf16* Ws[3] = {wqb, wkb, wvb};
  bf16* Ds[3] = {qb, kb, vb};

  const int t = threadIdx.x;
  const int lane = t & 63;
  const int w = t >> 6;
  const int wm = (w >> 1) * 32;     // wave tile: 32(m) x 32(n)
  const int wn = (w & 1) * 32;
  const int m0 = blockIdx.x * 64;
  const int n0 = blockIdx.y * 64;
  const int l15 = lane & 15;
  const int kq = lane >> 4;         // 0..3

  f32x4 acc[3][2][2] = {};

  for (int k0 = 0; k0 < KD; k0 += 64) {
    // A: 64x64 = 512 slots of 16B; 2 per thread
#pragma unroll
    for (int n = 0; n < 2; ++n) {
      const int s = n * 256 + t;
      const int row = s >> 3;                  // 0..63
      const int ch = (s & 7) ^ (row & 7);      // XOR bank swizzle
      gld16(xb + (size_t)(m0 + row) * KD + k0 + ch * 8, As + s * 8);
    }
    // B_j: 64x64 = 512 slots each; 2 per thread per output
#pragma unroll
    for (int j = 0; j < 3; ++j)
#pragma unroll
      for (int n = 0; n < 2; ++n) {
        const int s = n * 256 + t;
        const int row = s >> 3;                // 0..63
        const int ch = (s & 7) ^ (row & 7);
        gld16(Ws[j] + (size_t)(n0 + row) * KD + k0 + ch * 8, &Bs[j][s * 8]);
      }
    __syncthreads();
#pragma unroll
    for (int ks = 0; ks < 2; ++ks) {
      const int cb = ks * 4 + kq;              // k-chunk 0..7
      bf16x8 af[2];
#pragma unroll
      for (int mt = 0; mt < 2; ++mt) {
        const int row = wm + mt * 16 + l15;
        af[mt] = *(const bf16x8*)(As + row * 64 + ((cb ^ (row & 7)) * 8));
      }
#pragma unroll
      for (int j = 0; j < 3; ++j) {
        bf16x8 bfr[2];
#pragma unroll
        for (int nt = 0; nt < 2; ++nt) {
          const int row = wn + nt * 16 + l15;
          bfr[nt] = *(const bf16x8*)(&Bs[j][row * 64 + ((cb ^ (row & 7)) * 8)]);
        }
#pragma unroll
        for (int mt = 0; mt < 2; ++mt)
#pragma unroll
          for (int nt = 0; nt < 2; ++nt)
            acc[j][mt][nt] = __builtin_amdgcn_mfma_f32_16x16x32_bf16(af[mt], bfr[nt], acc[j][mt][nt], 0, 0, 0);
      }
    }
    __syncthreads();
  }
  // C/D layout: col = lane&15, row = (lane>>4)*4 + reg   [verified m89]
  const int colb = n0 + wn + l15;
  const int rowb = m0 + wm + (lane >> 4) * 4;
  const int odd = l15 & 1;
#pragma unroll
  for (int j = 0; j < 3; ++j) {
    bf16* D = Ds[j];
    const bool dorope = (j < 2);
#pragma unroll
    for (int mt = 0; mt < 2; ++mt)
#pragma unroll
      for (int nt = 0; nt < 2; ++nt) {
        const int col = colb + nt * 16;
        const int jj = (col & 63) >> 1;
#pragma unroll
        for (int rr = 0; rr < 4; ++rr) {
          float val = acc[j][mt][nt][rr];
          float other = __shfl_xor(val, 1);    // partner column value
          if (!odd) {
            const int row = rowb + mt * 16 + rr;
            float lo, hi;
            if (dorope) {
              float2 cs = rtab[(row & (SEQ_L - 1)) * 32 + jj];
              lo = val * cs.x - other * cs.y;  // out_re
              hi = val * cs.y + other * cs.x;  // out_im
            } else { lo = val; hi = other; }
            bf16x2 p; p[0] = (bf16)lo; p[1] = (bf16)hi;
            *(bf16x2*)(D + (size_t)row * ND + col) = p;
          }
        }
      }
  }
}

// ---- out-projection GEMM: 64x128 tile, BK=64, swizzled; grid (64,8) = 512 blocks ----
// Blocks x==0 / x==32 first materialize row-0 attention output from (pm,pz,pv).
__global__ __launch_bounds__(256, 2) void out_gemm_kernel(
    bf16* __restrict__ ab, const bf16* __restrict__ wob, float* __restrict__ out,
    const float* __restrict__ pm, const float* __restrict__ pz, const float* __restrict__ pv) {
  const int t = threadIdx.x;
  const int m0 = blockIdx.x * 64;
  const int n0 = blockIdx.y * 128;

  if (blockIdx.x == 0 || blockIdx.x == 32) {
    const int b = blockIdx.x == 0 ? 0 : 1;
#pragma unroll
    for (int e = t; e < DM; e += 256) {
      const int h = e >> 6, d = e & 63;
      const int base = b * 128 + h * 8;
      float M = -1e30f;
#pragma unroll
      for (int c = 0; c < 8; ++c) M = fmaxf(M, pm[base + c]);
      float Z = 0.f, od = 0.f;
#pragma unroll
      for (int c = 0; c < 8; ++c) {
        float sc = __expf(pm[base + c] - M);
        Z += pz[base + c] * sc;
        od += pv[(base + c) * 64 + d] * sc;
      }
      ab[(size_t)b * SEQ_L * DM + e] = (bf16)(od / Z);
    }
    __syncthreads();   // drain stores before staging reads the same row
  }

  __shared__ __align__(16) bf16 As[64 * 64];    // 8 KB
  __shared__ __align__(16) bf16 Bs[128 * 64];   // 16 KB
  const int lane = t & 63;
  const int wave = t >> 6;
  const int wm = (wave >> 1) * 32;
  const int wn = (wave & 1) * 64;
  const int l15 = lane & 15;
  const int kq = lane >> 4;

  f32x4 acc[2][4] = {};

  for (int k0 = 0; k0 < KD; k0 += 64) {
#pragma unroll
    for (int n = 0; n < 2; ++n) {
      const int s = n * 256 + t;               // 512 slots for As
      const int row = s >> 3;                  // 0..63
      const int ch = (s & 7) ^ (row & 7);
      gld16(ab + (size_t)(m0 + row) * KD + k0 + ch * 8, As + s * 8);
    }
#pragma unroll
    for (int n = 0; n < 4; ++n) {
      const int s = n * 256 + t;               // 1024 slots for Bs
      const int row = s >> 3;                  // 0..127
      const int ch = (s & 7) ^ (row & 7);
      gld16(wob + (size_t)(n0 + row) * KD + k0 + ch * 8, Bs + s * 8);
    }
    __syncthreads();
#pragma unroll
    for (int ks = 0; ks < 2; ++ks) {
      const int cb = ks * 4 + kq;
      bf16x8 af[2], bfr[4];
#pragma unroll
      for (int mt = 0; mt < 2; ++mt) {
        const int row = wm + mt * 16 + l15;
        af[mt] = *(const bf16x8*)(As + row * 64 + ((cb ^ (row & 7)) * 8));
      }
#pragma unroll
      for (int nt = 0; nt < 4; ++nt) {
        const int row = wn + nt * 16 + l15;
        bfr[nt] = *(const bf16x8*)(Bs + row * 64 + ((cb ^ (row & 7)) * 8));
      }
#pragma unroll
      for (int mt = 0; mt < 2; ++mt)
#pragma unroll
        for (int nt = 0; nt < 4; ++nt)
          acc[mt][nt] = __builtin_amdgcn_mfma_f32_16x16x32_bf16(af[mt], bfr[nt], acc[mt][nt], 0, 0, 0);
    }
    __syncthreads();
  }
  const int colb = n0 + wn + l15;
  const int rowb = m0 + wm + (lane >> 4) * 4;
#pragma unroll
  for (int mt = 0; mt < 2; ++mt)
#pragma unroll
    for (int nt = 0; nt < 4; ++nt)
#pragma unroll
      for (int rr = 0; rr < 4; ++rr)
        out[(size_t)(rowb + mt * 16 + rr) * ND + colb + nt * 16] = acc[mt][nt][rr];
}

// ---------------- attention ----------------
// grid (1280, 1), 256 threads.
//  bx < 256  : row-0 partials per (b, h, 256-col chunk) -> pm/pz/pv (dispatched FIRST: no tail).
//  bx >= 256 : sparse rows; wave handles one row i for ALL 16 heads (2KB wave-loads);
//              ALL 44 k+v load-quads prefetched into registers before any use (ILP).
__global__ __launch_bounds__(256, 2) void attn_kernel(const bf16* __restrict__ q, const bf16* __restrict__ k,
                                                      const bf16* __restrict__ v, bf16* __restrict__ o,
                                                      const int* __restrict__ ctab,
                                                      float* __restrict__ pm, float* __restrict__ pz,
                                                      float* __restrict__ pv) {
  const int t = threadIdx.x;
  const int lane = t & 63;
  const int w = t >> 6;

  __shared__ float sbuf[256];
  __shared__ float redm[4], redz[4];
  __shared__ float part[4][64];

  if (blockIdx.x >= 256) {
    const int sbx = blockIdx.x - 256;               // 0..1023
    const int b = sbx >> 9;
    const int tt = sbx & 511;
    const int tile = ((tt & 7) << 6) + (tt >> 3);   // XCD swizzle
    const int i = tile * 4 + 1 + w;
    if (i >= SEQ_L) return;   // wave-uniform
    const size_t bb = (size_t)b * SEQ_L * DM;
    const int eo = lane * 16;

    const bf16* qrow = q + bb + (size_t)i * DM + eo;
    bf16x8 qv0 = *(const bf16x8*)(qrow);
    bf16x8 qv1 = *(const bf16x8*)(qrow + 8);

    const int4* cp = (const int4*)(ctab + i * 12);
    int4 ca = cp[0], cb = cp[1], cc = cp[2];
    int cols[11] = {ca.x, ca.y, ca.z, ca.w, cb.x, cb.y, cb.z, cb.w, cc.x, cc.y, cc.z};

    // prefetch ALL k and v rows into registers (44 independent 16B loads in flight)
    bf16x8 kv[11][2], vv[11][2];
#pragma unroll
    for (int c = 0; c < 11; ++c) {
      int cj = cols[c] < 0 ? 0 : cols[c];
      const bf16* krow = k + bb + (size_t)cj * DM + eo;
      kv[c][0] = *(const bf16x8*)(krow);
      kv[c][1] = *(const bf16x8*)(krow + 8);
    }
#pragma unroll
    for (int c = 0; c < 11; ++c) {
      int cj = cols[c] < 0 ? 0 : cols[c];
      const bf16* vrow = v + bb + (size_t)cj * DM + eo;
      vv[c][0] = *(const bf16x8*)(vrow);
      vv[c][1] = *(const bf16x8*)(vrow + 8);
    }

    float sv[11];
#pragma unroll
    for (int c = 0; c < 11; ++c) {
      float acc = 0.f;
#pragma unroll
      for (int e = 0; e < 8; ++e)
        acc += (float)qv0[e] * (float)kv[c][0][e] + (float)qv1[e] * (float)kv[c][1][e];
      sv[c] = acc;
    }
#pragma unroll
    for (int c = 0; c < 11; ++c) {
      sv[c] += __shfl_xor(sv[c], 1);
      sv[c] += __shfl_xor(sv[c], 2);
      sv[c] = cols[c] < 0 ? -1e30f : sv[c] * 0.125f;
    }
    float m = -1e30f;
#pragma unroll
    for (int c = 0; c < 11; ++c) m = fmaxf(m, sv[c]);
    float z = 0.f;
#pragma unroll
    for (int c = 0; c < 11; ++c) { sv[c] = __expf(sv[c] - m); z += sv[c]; }
    const float inv = 1.f / z;

    float oa[16] = {};
#pragma unroll
    for (int c = 0; c < 11; ++c) {
#pragma unroll
      for (int e = 0; e < 8; ++e) {
        oa[e]     += sv[c] * (float)vv[c][0][e];
        oa[8 + e] += sv[c] * (float)vv[c][1][e];
      }
    }
    bf16x8 ov0, ov1;
#pragma unroll
    for (int e = 0; e < 8; ++e) {
      ov0[e] = (bf16)(oa[e] * inv);
      ov1[e] = (bf16)(oa[8 + e] * inv);
    }
    bf16* orow = o + bb + (size_t)i * DM + eo;
    *(bf16x8*)(orow) = ov0;
    *(bf16x8*)(orow + 8) = ov1;
    return;
  }

  // ---- row-0 partial: (b, h, chunk of 256 cols) ----
  const int idx = blockIdx.x;           // 0..255
  const int b = idx >> 7;
  const int rem = idx & 127;
  const int h = rem >> 3;
  const int c = rem & 7;
  const size_t hb = (size_t)b * SEQ_L * DM + (size_t)h * HD;
  const int j = c * 256 + t;

  bf16x8 qv8[8];
#pragma unroll
  for (int cc = 0; cc < 8; ++cc) qv8[cc] = *(const bf16x8*)(q + hb + cc * 8);

  float acc = 0.f;
#pragma unroll
  for (int cc = 0; cc < 8; ++cc) {
    bf16x8 kv = *(const bf16x8*)(k + hb + (size_t)j * DM + cc * 8);
#pragma unroll
    for (int e = 0; e < 8; ++e) acc += (float)qv8[cc][e] * (float)kv[e];
  }
  float s = acc * 0.125f;
  float mloc = s;
#pragma unroll
  for (int off = 32; off > 0; off >>= 1) mloc = fmaxf(mloc, __shfl_xor(mloc, off));
  if (lane == 0) redm[w] = mloc;
  __syncthreads();
  const float m = fmaxf(fmaxf(redm[0], redm[1]), fmaxf(redm[2], redm[3]));

  float e = __expf(s - m);
  sbuf[t] = e;
  float zloc = e;
#pragma unroll
  for (int off = 32; off > 0; off >>= 1) zloc += __shfl_xor(zloc, off);
  if (lane == 0) redz[w] = zloc;
  __syncthreads();
  const float zc = redz[0] + redz[1] + redz[2] + redz[3];

  float oa = 0.f;
  for (int jj = w; jj < 256; jj += 4)
    oa += sbuf[jj] * (float)v[hb + (size_t)(c * 256 + jj) * DM + lane];
  part[w][lane] = oa;
  __syncthreads();
  if (t < 64) pv[idx * 64 + t] = part[0][t] + part[1][t] + part[2][t] + part[3][t];
  if (t == 0) { pm[idx] = m; pz[idx] = zc; }
}

// ---------------- launch ----------------
extern "C" void kernel_launch(void* const* d_in, const int* in_sizes, int n_in,
                              void* d_out, int out_size, void* d_ws, size_t ws_size,
                              hipStream_t stream) {
  const float* x     = (const float*)d_in[0];
  const float* freqs = (const float*)d_in[1];
  const float* wq    = (const float*)d_in[2];
  const float* wk    = (const float*)d_in[3];
  const float* wv    = (const float*)d_in[4];
  const float* wo    = (const float*)d_in[5];
  float* out = (float*)d_out;

  char* ws = (char*)d_ws;
  bf16* xb  = (bf16*)(ws + 0);          // 8 MiB
  bf16* wqb = (bf16*)(ws + 8388608);    // 2 MiB each
  bf16* wkb = (bf16*)(ws + 10485760);
  bf16* wvb = (bf16*)(ws + 12582912);
  bf16* wob = (bf16*)(ws + 14680064);
  bf16* qb  = (bf16*)(ws + 16777216);   // 8 MiB [B,L,H,HD]
  bf16* kb  = (bf16*)(ws + 25165824);
  bf16* vb  = (bf16*)(ws + 33554432);
  bf16* ab  = (bf16*)(ws + 41943040);   // 8 MiB; end 48 MiB
  int*    ctab = (int*)(ws + 50331648); // 96 KB
  float*  pm   = (float*)(ws + 50462720);
  float*  pz   = (float*)(ws + 50463744);
  float*  pv   = (float*)(ws + 50464768);   // 64 KB
  float2* rtab = (float2*)(ws + 50593792);  // 512 KB rope cos/sin table
  (void)ws_size;

  prep_kernel<<<8456, 256, 0, stream>>>(x, wq, wk, wv, wo, freqs, xb, wqb, wkb, wvb, wob, ctab, rtab);
  qkv_gemm_kernel<<<dim3(64, 16), 256, 0, stream>>>(xb, wqb, wkb, wvb, qb, kb, vb, rtab);
  attn_kernel<<<dim3(1280, 1), 256, 0, stream>>>(qb, kb, vb, ab, ctab, pm, pz, pv);
  out_gemm_kernel<<<dim3(64, 8), 256, 0, stream>>>(ab, wob, out, pm, pz, pv);
}